// Round 7
// baseline (218.013 us; speedup 1.0000x reference)
//
#include <hip/hip_runtime.h>
#include <hip/hip_bf16.h>

typedef short bf16x8 __attribute__((ext_vector_type(8)));
typedef float f32x4  __attribute__((ext_vector_type(4)));

#define E_TOT   6572
#define E4_TOT  1643
#define RSDW    68      // LDS row stride in dwords (272 B): b128 rows spread banks

// d_ws layout (ushort indices): [0,12288) W0p | [12288,24576) W1p |
// [24576,182304) em0b [6572][24] | [182304,261168) em1b [1643][48]
#define EM0B_OFF 24576
#define EM1B_OFF 182304

static __device__ __forceinline__ unsigned pkrn(float a, float b) {
    union { __hip_bfloat162 h; unsigned u; } v;
    v.h = __float22bfloat162_rn(float2{a, b});    // v_cvt_pk_bf16_f32
    return v.u;
}
static __device__ __forceinline__ float clamp01(float v) {
    return __builtin_amdgcn_fmed3f(v, 0.0f, 1.0f);
}
// lerp two packed-bf16 dwords (a=row0, b=row1) with fp32 weight p -> packed bf16
static __device__ __forceinline__ unsigned lerp_dw(unsigned a, unsigned b, float p) {
    float alo = __uint_as_float(a << 16);
    float ahi = __uint_as_float(a & 0xffff0000u);
    float blo = __uint_as_float(b << 16);
    float bhi = __uint_as_float(b & 0xffff0000u);
    return pkrn(fmaf(p, blo - alo, alo), fmaf(p, bhi - ahi, ahi));
}

// Pack W0p/W1p in MFMA fragment order:
//   frag(t,s), lane l, elem e  <-  W[k = 32s + 8*(l>>4) + e][n = 16t + (l&15)]
// (W0 K padded 66->96; rows 66,67 duplicate rows 0,1 for the Dekker-x term)
// plus bf16 copies of em0_w (rows padded 20->24) and em1_w (44->48).
__global__ void pack_all(const float* __restrict__ W0, const float* __restrict__ W1,
                         const float* __restrict__ em0_w, const float* __restrict__ em1_w,
                         unsigned short* __restrict__ ws)
{
    int id = blockIdx.x * 256 + threadIdx.x;
    if (id >= 261168) return;
    union { __hip_bfloat16 h; unsigned short u; } cv;
    if (id < 12288) {                              // W0p: f = t*3+s, t<8, s<3
        int e = id & 7, l = (id >> 3) & 63, f = id >> 9;
        int g = l >> 4, c = l & 15;
        int s = f % 3, t = f / 3;
        int k = s * 32 + g * 8 + e, n = t * 16 + c;
        float v = (k < 66) ? W0[k * 128 + n]
                : ((k < 68) ? W0[(k - 66) * 128 + n] : 0.0f);
        cv.h = __float2bfloat16(v);
        ws[id] = cv.u;
    } else if (id < 24576) {                       // W1p: f = t*4+s, t<6, s<4
        int id1 = id - 12288;
        int e = id1 & 7, l = (id1 >> 3) & 63, f = id1 >> 9;
        int g = l >> 4, c = l & 15;
        int s = f & 3, t = f >> 2;
        int k = s * 32 + g * 8 + e, n = t * 16 + c;
        cv.h = __float2bfloat16(W1[k * 96 + n]);
        ws[id] = cv.u;
    } else if (id < EM1B_OFF) {                    // em0b [6572][24]
        int q = id - EM0B_OFF;
        int row = q / 24, col = q - row * 24;
        cv.h = __float2bfloat16(col < 20 ? em0_w[row * 20 + col] : 0.0f);
        ws[id] = cv.u;
    } else {                                       // em1b [1643][48]
        int q = id - EM1B_OFF;
        int row = q / 48, col = q - row * 48;
        cv.h = __float2bfloat16(col < 44 ? em1_w[row * 44 + col] : 0.0f);
        ws[id] = cv.u;
    }
}

// Persistent single-wave blocks; grid-stride over 64-point batches with a
// cross-batch prefetch pipeline: while batch b computes, table-gathers for
// b+stride and emb/x for b+2*stride are in flight.
__global__ __launch_bounds__(64, 2) void fused_mlp(
    const float* __restrict__ x, const float* __restrict__ emb,
    const float* __restrict__ b0, const float* __restrict__ b1,
    const float* __restrict__ W2, const float* __restrict__ b2,
    const unsigned short* __restrict__ ws,
    float* __restrict__ out, int N, int NB, int stride)
{
    __shared__ __align__(16) char smem[64 * RSDW * 4];  // 17408 B: features/h1T
    const unsigned short* W0p  = ws;
    const unsigned short* W1p  = ws + 12288;
    const unsigned short* em0b = ws + EM0B_OFF;
    const unsigned short* em1b = ws + EM1B_OFF;

    const int lane = threadIdx.x;                 // one wave per block
    const int g    = lane >> 4, c = lane & 15;
    const float b2s = b2[0];

    uint4 e0[6];                                  // em0 rows i0,i0+1 (96 B)
    uint4 e1[12];                                 // em1 rows jb,jb+1 (192 B)

    // issue the 18 region gathers for a batch whose emb value is tv
    auto issue_gather = [&](float tv) {
        const int i0 = (int)tv;
        const int jb = min((int)(tv * 0.25f), E4_TOT - 2);
        const uint4* R0 = (const uint4*)(em0b + i0 * 24);
        #pragma unroll
        for (int v = 0; v < 6; ++v) e0[v] = R0[v];
        const uint4* R1 = (const uint4*)(em1b + jb * 48);
        #pragma unroll
        for (int v = 0; v < 12; ++v) e1[v] = R1[v];
    };

    // ---- prologue: batch b in flight, emb/x for bn in flight --------------
    int b  = blockIdx.x;
    int bn = b + stride;
    float t_cur, t_nxt;  float2 x_cur, x_nxt;
    {
        const int pb = min(b * 64 + lane, N - 1);
        t_cur = emb[pb];
        x_cur = *(const float2*)(x + 2 * pb);
        issue_gather(t_cur);
        const int pn = min(min(bn, NB - 1) * 64 + lane, N - 1);
        t_nxt = emb[pn];
        x_nxt = *(const float2*)(x + 2 * pn);
    }

    for (;;) {
        // ---- Phase A: lerp current batch, write feature row ---------------
        // k-layout: [0,1]=bf16(x) [2..21]=em0 [22..65]=em1 [66,67]=x_lo [68..95]=0
        {
            const int   i0 = (int)t_cur;
            const float pf = t_cur - (float)i0;
            const float t4 = t_cur * 0.25f;
            const int   j0 = (int)t4;
            float qf = (j0 >= E4_TOT - 1) ? 1.0f : (t4 - (float)j0);

            union { __hip_bfloat16 h; unsigned short u; } x0, x1;
            x0.h = __float2bfloat16(x_cur.x);
            x1.h = __float2bfloat16(x_cur.y);

            unsigned d[48];
            d[0]  = (unsigned)x0.u | ((unsigned)x1.u << 16);
            const unsigned* a0dw = (const unsigned*)e0;   // [0..11] r0, [12..23] r1
            #pragma unroll
            for (int i = 0; i < 10; ++i)
                d[1 + i] = lerp_dw(a0dw[i], a0dw[12 + i], pf);
            const unsigned* b0dw = (const unsigned*)e1;   // [0..23] r0, [24..47] r1
            #pragma unroll
            for (int i = 0; i < 22; ++i)
                d[11 + i] = lerp_dw(b0dw[i], b0dw[24 + i], qf);
            d[33] = pkrn(x_cur.x - __bfloat162float(x0.h),
                         x_cur.y - __bfloat162float(x1.h));
            #pragma unroll
            for (int i = 34; i < 48; ++i) d[i] = 0u;

            uint4* rw = (uint4*)(smem + lane * (RSDW * 4));
            #pragma unroll
            for (int ch = 0; ch < 12; ++ch)
                rw[ch] = make_uint4(d[4*ch], d[4*ch+1], d[4*ch+2], d[4*ch+3]);
        }

        // ---- feature B-frags to regs (frees LDS region for h1T) -----------
        bf16x8 a0f[4][3];
        #pragma unroll
        for (int mt = 0; mt < 4; ++mt)
            #pragma unroll
            for (int s = 0; s < 3; ++s)
                a0f[mt][s] = *(const bf16x8*)(smem + ((16*mt + c) * RSDW + 16*s + 4*g) * 4);

        // ---- prefetch rotation: gathers for bn, emb/x for bn+stride -------
        const bool more = (bn < NB);
        issue_gather(t_nxt);                       // e0/e1 now belong to bn
        const int b2n = min(bn + stride, NB - 1);
        const int p2  = min(b2n * 64 + lane, N - 1);
        const float  t_n2 = emb[p2];
        const float2 x_n2 = *(const float2*)(x + 2 * p2);

        // ---- Layer 0 (swapped): D0[out][pt] -> h1T[pt][out] as b64 --------
        #pragma unroll
        for (int t = 0; t < 8; ++t) {
            bf16x8 bw[3];
            #pragma unroll
            for (int s = 0; s < 3; ++s)
                bw[s] = *(const bf16x8*)(W0p + ((t*3 + s) << 9) + (lane << 3));
            const float4 b0v = *(const float4*)(b0 + t*16 + g*4);
            f32x4 acc[4];
            #pragma unroll
            for (int mt = 0; mt < 4; ++mt) acc[mt] = f32x4{b0v.x, b0v.y, b0v.z, b0v.w};
            #pragma unroll
            for (int s = 0; s < 3; ++s)
                #pragma unroll
                for (int mt = 0; mt < 4; ++mt)
                    acc[mt] = __builtin_amdgcn_mfma_f32_16x16x32_bf16(bw[s], a0f[mt][s], acc[mt], 0, 0, 0);
            #pragma unroll
            for (int mt = 0; mt < 4; ++mt) {
                unsigned P0 = pkrn(clamp01(acc[mt][0]), clamp01(acc[mt][1]));
                unsigned P1 = pkrn(clamp01(acc[mt][2]), clamp01(acc[mt][3]));
                *(uint2*)(smem + ((16*mt + c) * RSDW + 8*t + 2*g) * 4) = make_uint2(P0, P1);
            }
        }
        __syncthreads();                           // 1-wave: near-free

        bf16x8 hb[4][4];
        #pragma unroll
        for (int s1 = 0; s1 < 4; ++s1)
            #pragma unroll
            for (int mt = 0; mt < 4; ++mt)
                hb[s1][mt] = *(const bf16x8*)(smem + ((16*mt + c) * RSDW + 16*s1 + 4*g) * 4);

        // ---- Layer 1 (swapped) + fused W2 ---------------------------------
        float zp[4] = {0.f, 0.f, 0.f, 0.f};
        #pragma unroll
        for (int t1 = 0; t1 < 6; ++t1) {
            bf16x8 bw1[4];
            #pragma unroll
            for (int s1 = 0; s1 < 4; ++s1)
                bw1[s1] = *(const bf16x8*)(W1p + ((t1*4 + s1) << 9) + (lane << 3));
            const float4 b1v = *(const float4*)(b1 + t1*16 + g*4);
            f32x4 acc[4];
            #pragma unroll
            for (int mt = 0; mt < 4; ++mt) acc[mt] = f32x4{b1v.x, b1v.y, b1v.z, b1v.w};
            #pragma unroll
            for (int s1 = 0; s1 < 4; ++s1)
                #pragma unroll
                for (int mt = 0; mt < 4; ++mt)
                    acc[mt] = __builtin_amdgcn_mfma_f32_16x16x32_bf16(bw1[s1], hb[s1][mt], acc[mt], 0, 0, 0);
            const float4 w2v = *(const float4*)(W2 + t1*16 + g*4);
            #pragma unroll
            for (int mt = 0; mt < 4; ++mt) {
                zp[mt] = fmaf(clamp01(acc[mt][0]), w2v.x, zp[mt]);
                zp[mt] = fmaf(clamp01(acc[mt][1]), w2v.y, zp[mt]);
                zp[mt] = fmaf(clamp01(acc[mt][2]), w2v.z, zp[mt]);
                zp[mt] = fmaf(clamp01(acc[mt][3]), w2v.w, zp[mt]);
            }
        }

        // ---- reduce over g-groups, select, sigmoid, store -----------------
        float zr[4];
        #pragma unroll
        for (int mt = 0; mt < 4; ++mt) {
            float v = zp[mt];
            v += __shfl_xor(v, 16);
            v += __shfl_xor(v, 32);
            zr[mt] = v;
        }
        float z = (g == 0) ? zr[0] : (g == 1) ? zr[1] : (g == 2) ? zr[2] : zr[3];
        z += b2s;
        z = 1.0f / (1.0f + __expf(-z));
        const int pst = b * 64 + lane;             // pt = 16g+c = lane
        if (pst < N) out[pst] = z;

        if (!more) break;
        b = bn; bn += stride;
        t_cur = t_nxt; x_cur = x_nxt;
        t_nxt = t_n2;  x_nxt = x_n2;
    }
}

extern "C" void kernel_launch(void* const* d_in, const int* in_sizes, int n_in,
                              void* d_out, int out_size, void* d_ws, size_t ws_size,
                              hipStream_t stream) {
    const float* x     = (const float*)d_in[0];
    const float* emb   = (const float*)d_in[1];
    const float* em0_w = (const float*)d_in[2];
    const float* em1_w = (const float*)d_in[3];
    const float* W0    = (const float*)d_in[4];
    const float* b0    = (const float*)d_in[5];
    const float* W1    = (const float*)d_in[6];
    const float* b1    = (const float*)d_in[7];
    const float* W2    = (const float*)d_in[8];
    const float* b2    = (const float*)d_in[9];
    float* out = (float*)d_out;
    const int N = in_sizes[1];

    unsigned short* ws = (unsigned short*)d_ws;   // 522336 B used

    pack_all<<<1021, 256, 0, stream>>>(W0, W1, em0_w, em1_w, ws);
    const int NB = (N + 63) / 64;                 // 15625 batches
    const int PERS = 2304;                        // 9 blocks/CU x 256 CU
    const int nb = (NB < PERS) ? NB : PERS;
    fused_mlp<<<nb, 64, 0, stream>>>(x, emb, b0, b1, W2, b2, ws, out, N, NB, nb);
}

// Round 8
// 101.128 us; speedup vs baseline: 2.1558x; 2.1558x over previous
//
#include <hip/hip_runtime.h>
#include <hip/hip_bf16.h>

typedef short bf16x8 __attribute__((ext_vector_type(8)));
typedef short bf16x4 __attribute__((ext_vector_type(4)));
typedef float f32x4  __attribute__((ext_vector_type(4)));

#define E_TOT   6572
#define E4_TOT  1643
#define RSDW    52      // LDS row stride dwords (208 B): 16B-aligned, 2-way banks max

// d_ws layout (ushort indices): [0,12288) W0p | [12288,24576) W1p16 |
// [24576,182304) em0b [6572][24] | [182304,261168) em1b [1643][48]
#define EM0B_OFF 24576
#define EM1B_OFF 182304

#if __has_builtin(__builtin_amdgcn_mfma_f32_16x16x16bf16_1k)
static __device__ __forceinline__ f32x4 MFMA16(bf16x4 a, bf16x4 b, f32x4 c) {
    return __builtin_amdgcn_mfma_f32_16x16x16bf16_1k(a, b, c, 0, 0, 0);
}
#else
static __device__ __forceinline__ f32x4 MFMA16(bf16x4 a, bf16x4 b, f32x4 c) {
    f32x4 d;
    asm volatile("v_mfma_f32_16x16x16_bf16 %0, %1, %2, %3"
                 : "=v"(d) : "v"(a), "v"(b), "v"(c));
    return d;
}
#endif

static __device__ __forceinline__ unsigned pkrn(float a, float b) {
    union { __hip_bfloat162 h; unsigned u; } v;
    v.h = __float22bfloat162_rn(float2{a, b});    // v_cvt_pk_bf16_f32
    return v.u;
}
static __device__ __forceinline__ float clamp01(float v) {
    return __builtin_amdgcn_fmed3f(v, 0.0f, 1.0f);
}
// lerp two packed-bf16 dwords (a=row0, b=row1) with fp32 weight p -> packed bf16
static __device__ __forceinline__ unsigned lerp_dw(unsigned a, unsigned b, float p) {
    float alo = __uint_as_float(a << 16);
    float ahi = __uint_as_float(a & 0xffff0000u);
    float blo = __uint_as_float(b << 16);
    float bhi = __uint_as_float(b & 0xffff0000u);
    return pkrn(fmaf(p, blo - alo, alo), fmaf(p, bhi - ahi, ahi));
}

// W0p: 16x16x32 A-operand frag order (as before):
//   frag(t,s), lane l, elem e  <-  W0[k = 32s + 8*(l>>4) + e][n = 16t + (l&15)]
//   (K padded 66->96; rows 66,67 duplicate rows 0,1 for the Dekker-x term)
// W1p16: 16x16x16 A-operand frag order:
//   frag f = 6*s1 + t1, lane l, elem e2<4  <-  W1[k = 16s1 + 4*(l>>4) + e2][n = 16t1 + (l&15)]
// plus bf16 copies of em0_w (rows padded 20->24) and em1_w (44->48).
__global__ void pack_all(const float* __restrict__ W0, const float* __restrict__ W1,
                         const float* __restrict__ em0_w, const float* __restrict__ em1_w,
                         unsigned short* __restrict__ ws)
{
    int id = blockIdx.x * 256 + threadIdx.x;
    if (id >= 261168) return;
    union { __hip_bfloat16 h; unsigned short u; } cv;
    if (id < 12288) {                              // W0p: f = t*3+s, t<8, s<3
        int e = id & 7, l = (id >> 3) & 63, f = id >> 9;
        int g = l >> 4, c = l & 15;
        int s = f % 3, t = f / 3;
        int k = s * 32 + g * 8 + e, n = t * 16 + c;
        float v = (k < 66) ? W0[k * 128 + n]
                : ((k < 68) ? W0[(k - 66) * 128 + n] : 0.0f);
        cv.h = __float2bfloat16(v);
        ws[id] = cv.u;
    } else if (id < 24576) {                       // W1p16: f = 6*s1 + t1, s1<8, t1<6
        int id1 = id - 12288;
        int e2 = id1 & 3, l = (id1 >> 2) & 63, f = id1 >> 8;
        int g = l >> 4, c = l & 15;
        int s1 = f / 6, t1 = f - 6 * s1;
        int k = 16 * s1 + 4 * g + e2, n = 16 * t1 + c;
        cv.h = __float2bfloat16(W1[k * 96 + n]);
        ws[id] = cv.u;
    } else if (id < EM1B_OFF) {                    // em0b [6572][24]
        int q = id - EM0B_OFF;
        int row = q / 24, col = q - row * 24;
        cv.h = __float2bfloat16(col < 20 ? em0_w[row * 20 + col] : 0.0f);
        ws[id] = cv.u;
    } else {                                       // em1b [1643][48]
        int q = id - EM1B_OFF;
        int row = q / 48, col = q - row * 48;
        cv.h = __float2bfloat16(col < 44 ? em1_w[row * 44 + col] : 0.0f);
        ws[id] = cv.u;
    }
}

// Swapped-operand MFMA MLP. Layer 0: 16x16x32, D0[out][pt]. Layer 1: 16x16x16,
// whose B-frag (k = 16s1+4g+e) is EXACTLY layer-0's D-quad (out = 16t+4g+r,
// t=s1, e=r) in the SAME lane -> h1 never touches LDS; LDS holds features only.
__global__ __launch_bounds__(64, 2) void fused_mlp(
    const float* __restrict__ x, const float* __restrict__ emb,
    const float* __restrict__ b0, const float* __restrict__ b1,
    const float* __restrict__ W2, const float* __restrict__ b2,
    const unsigned short* __restrict__ ws,
    float* __restrict__ out, int N)
{
    __shared__ __align__(16) char smem[64 * RSDW * 4];  // 13312 B: features only
    const unsigned short* W0p   = ws;
    const unsigned short* W1p16 = ws + 12288;
    const unsigned short* em0b  = ws + EM0B_OFF;
    const unsigned short* em1b  = ws + EM1B_OFF;

    const int lane = threadIdx.x;                 // one wave per block
    const int g    = lane >> 4, c = lane & 15;
    const int p    = blockIdx.x * 64 + lane;
    const int pc   = min(p, N - 1);

    // ---- Phase A: gather bf16 table regions, lerp, write feature row ------
    // k-layout: [0,1]=bf16(x) [2..21]=em0 [22..65]=em1 [66,67]=x_lo [68..95]=0
    {
        const float t  = emb[pc];
        const int   i0 = (int)t;                  // i0 <= 6570 -> i0+1 valid
        const float pf = t - (float)i0;
        const float t4 = t * 0.25f;               // exact
        const int   j0 = (int)t4;
        int   jbase = j0;  float qf = t4 - (float)j0;
        if (j0 >= E4_TOT - 1) { jbase = E4_TOT - 2; qf = 1.0f; }

        uint4 e0[6];                              // em0b rows i0,i0+1 (96 B)
        const uint4* R0 = (const uint4*)(em0b + i0 * 24);
        #pragma unroll
        for (int v = 0; v < 6; ++v) e0[v] = R0[v];
        uint4 e1[12];                             // em1b rows jbase,jbase+1 (192 B)
        const uint4* R1 = (const uint4*)(em1b + jbase * 48);
        #pragma unroll
        for (int v = 0; v < 12; ++v) e1[v] = R1[v];

        const float2 xv = *(const float2*)(x + 2 * pc);
        union { __hip_bfloat16 h; unsigned short u; } x0, x1;
        x0.h = __float2bfloat16(xv.x);
        x1.h = __float2bfloat16(xv.y);

        unsigned d[48];
        d[0]  = (unsigned)x0.u | ((unsigned)x1.u << 16);
        const unsigned* a0dw = (const unsigned*)e0;     // [0..11] r0, [12..23] r1
        #pragma unroll
        for (int i = 0; i < 10; ++i)
            d[1 + i] = lerp_dw(a0dw[i], a0dw[12 + i], pf);
        const unsigned* b0dw = (const unsigned*)e1;     // [0..23] r0, [24..47] r1
        #pragma unroll
        for (int i = 0; i < 22; ++i)
            d[11 + i] = lerp_dw(b0dw[i], b0dw[24 + i], qf);
        d[33] = pkrn(xv.x - __bfloat162float(x0.h), xv.y - __bfloat162float(x1.h));
        #pragma unroll
        for (int i = 34; i < 48; ++i) d[i] = 0u;

        uint4* rw = (uint4*)(smem + lane * (RSDW * 4));
        #pragma unroll
        for (int ch = 0; ch < 12; ++ch)
            rw[ch] = make_uint4(d[4*ch], d[4*ch+1], d[4*ch+2], d[4*ch+3]);
    }
    // no barrier: all LDS traffic is wave-local; lgkmcnt orders it

    // ---- feature B-frags: lane (g,c) <- feat[k=32s+8g+e][pt=16mt+c] --------
    bf16x8 a0f[4][3];
    #pragma unroll
    for (int mt = 0; mt < 4; ++mt)
        #pragma unroll
        for (int s = 0; s < 3; ++s)
            a0f[mt][s] = *(const bf16x8*)(smem + ((16*mt + c) * RSDW + 16*s + 4*g) * 4);

    // ---- Layer 0 (16x16x32, swapped): D0[out=16t+4g+r][pt=16mt+c] ----------
    // clamp + pack each D-quad -> pb[t][mt] = h1 bf16, ready as L1 B-frags.
    union U2S { uint2 u; bf16x4 s; };
    bf16x4 pb[8][4];
    #pragma unroll
    for (int t = 0; t < 8; ++t) {
        bf16x8 bw[3];
        #pragma unroll
        for (int s = 0; s < 3; ++s)
            bw[s] = *(const bf16x8*)(W0p + ((t*3 + s) << 9) + (lane << 3));
        const float4 b0v = *(const float4*)(b0 + t*16 + g*4);   // b0[16t+4g+r]
        f32x4 acc[4];
        #pragma unroll
        for (int mt = 0; mt < 4; ++mt) acc[mt] = f32x4{b0v.x, b0v.y, b0v.z, b0v.w};
        #pragma unroll
        for (int s = 0; s < 3; ++s)
            #pragma unroll
            for (int mt = 0; mt < 4; ++mt)
                acc[mt] = __builtin_amdgcn_mfma_f32_16x16x32_bf16(bw[s], a0f[mt][s], acc[mt], 0, 0, 0);
        #pragma unroll
        for (int mt = 0; mt < 4; ++mt) {
            U2S u2;
            u2.u = make_uint2(pkrn(clamp01(acc[mt][0]), clamp01(acc[mt][1])),
                              pkrn(clamp01(acc[mt][2]), clamp01(acc[mt][3])));
            pb[t][mt] = u2.s;                     // h1[k=16t+4g+e][pt=16mt+c]
        }
    }

    // ---- Layer 1 (16x16x16, swapped) + fused W2, no LDS --------------------
    float zp[4] = {0.f, 0.f, 0.f, 0.f};
    #pragma unroll
    for (int t1 = 0; t1 < 6; ++t1) {
        const float4 b1v = *(const float4*)(b1 + t1*16 + g*4);  // b1[16t1+4g+r]
        f32x4 acc[4];
        #pragma unroll
        for (int mt = 0; mt < 4; ++mt) acc[mt] = f32x4{b1v.x, b1v.y, b1v.z, b1v.w};
        #pragma unroll
        for (int s1 = 0; s1 < 8; ++s1) {
            const bf16x4 bw1 = *(const bf16x4*)(W1p16 + ((s1*6 + t1) << 8) + (lane << 2));
            #pragma unroll
            for (int mt = 0; mt < 4; ++mt)
                acc[mt] = MFMA16(bw1, pb[s1][mt], acc[mt]);
        }
        const float4 w2v = *(const float4*)(W2 + t1*16 + g*4);  // W2[16t1+4g+r]
        #pragma unroll
        for (int mt = 0; mt < 4; ++mt) {
            zp[mt] = fmaf(clamp01(acc[mt][0]), w2v.x, zp[mt]);
            zp[mt] = fmaf(clamp01(acc[mt][1]), w2v.y, zp[mt]);
            zp[mt] = fmaf(clamp01(acc[mt][2]), w2v.z, zp[mt]);
            zp[mt] = fmaf(clamp01(acc[mt][3]), w2v.w, zp[mt]);
        }
    }

    // ---- reduce over g-groups (4 lanes per pt-column), sigmoid, store ------
    float zr[4];
    #pragma unroll
    for (int mt = 0; mt < 4; ++mt) {
        float v = zp[mt];
        v += __shfl_xor(v, 16);
        v += __shfl_xor(v, 32);
        zr[mt] = v;                               // full z for pt=16mt+c
    }
    float z = (g == 0) ? zr[0] : (g == 1) ? zr[1] : (g == 2) ? zr[2] : zr[3];
    z += b2[0];
    z = 1.0f / (1.0f + __expf(-z));
    if (p < N) out[p] = z;                        // pt = 16g+c = lane: coalesced
}

extern "C" void kernel_launch(void* const* d_in, const int* in_sizes, int n_in,
                              void* d_out, int out_size, void* d_ws, size_t ws_size,
                              hipStream_t stream) {
    const float* x     = (const float*)d_in[0];
    const float* emb   = (const float*)d_in[1];
    const float* em0_w = (const float*)d_in[2];
    const float* em1_w = (const float*)d_in[3];
    const float* W0    = (const float*)d_in[4];
    const float* b0    = (const float*)d_in[5];
    const float* W1    = (const float*)d_in[6];
    const float* b1    = (const float*)d_in[7];
    const float* W2    = (const float*)d_in[8];
    const float* b2    = (const float*)d_in[9];
    float* out = (float*)d_out;
    const int N = in_sizes[1];

    unsigned short* ws = (unsigned short*)d_ws;   // 522336 B used

    pack_all<<<1021, 256, 0, stream>>>(W0, W1, em0_w, em1_w, ws);
    const int nb = (N + 63) / 64;
    fused_mlp<<<nb, 64, 0, stream>>>(x, emb, b0, b1, W2, b2, ws, out, N);
}

// Round 9
// 88.416 us; speedup vs baseline: 2.4658x; 1.1438x over previous
//
#include <hip/hip_runtime.h>
#include <hip/hip_bf16.h>

typedef short bf16x8 __attribute__((ext_vector_type(8)));
typedef short bf16x4 __attribute__((ext_vector_type(4)));
typedef float f32x4  __attribute__((ext_vector_type(4)));

#define E_TOT   6572
#define E4_TOT  1643
#define RSDW    52      // LDS row stride dwords (208 B): 16B-aligned, 2-way banks max

// d_ws layout (ushort indices): [0,12288) W0p | [12288,24576) W1p16 (paired) |
// [24576,182304) em0b [6572][24] | [182304,261168) em1b [1643][48]
#define EM0B_OFF 24576
#define EM1B_OFF 182304

#if __has_builtin(__builtin_amdgcn_mfma_f32_16x16x16bf16_1k)
static __device__ __forceinline__ f32x4 MFMA16(bf16x4 a, bf16x4 b, f32x4 c) {
    return __builtin_amdgcn_mfma_f32_16x16x16bf16_1k(a, b, c, 0, 0, 0);
}
#else
static __device__ __forceinline__ f32x4 MFMA16(bf16x4 a, bf16x4 b, f32x4 c) {
    f32x4 d;
    asm volatile("v_mfma_f32_16x16x16_bf16 %0, %1, %2, %3"
                 : "=v"(d) : "v"(a), "v"(b), "v"(c));
    return d;
}
#endif

static __device__ __forceinline__ unsigned pkrn(float a, float b) {
    union { __hip_bfloat162 h; unsigned u; } v;
    v.h = __float22bfloat162_rn(float2{a, b});    // v_cvt_pk_bf16_f32
    return v.u;
}
static __device__ __forceinline__ float clamp01(float v) {
    return __builtin_amdgcn_fmed3f(v, 0.0f, 1.0f);
}
// lerp two packed-bf16 dwords (a=row0, b=row1) with fp32 weight p -> packed bf16
static __device__ __forceinline__ unsigned lerp_dw(unsigned a, unsigned b, float p) {
    float alo = __uint_as_float(a << 16);
    float ahi = __uint_as_float(a & 0xffff0000u);
    float blo = __uint_as_float(b << 16);
    float bhi = __uint_as_float(b & 0xffff0000u);
    return pkrn(fmaf(p, blo - alo, alo), fmaf(p, bhi - ahi, ahi));
}

// W0p: 16x16x32 A-operand frag order:
//   frag(t,s), lane l, elem e  <-  W0[k = 32s + 8*(l>>4) + e][n = 16t + (l&15)]
//   (K padded 66->96; rows 66,67 duplicate rows 0,1 for the Dekker-x term)
// W1p16 (PAIRED 16x16x16 A-frags): pair p2 = q*6 + t1 (q<4, t1<6), lane l,
//   half h, elem e2<4  <-  W1[k = 16*(2q+h) + 4*(l>>4) + e2][n = 16t1 + (l&15)]
//   offset = p2*512 + l*8 + h*4 + e2  -> one b128 load serves s1=2q,2q+1.
// plus bf16 copies of em0_w (rows padded 20->24) and em1_w (44->48).
__global__ void pack_all(const float* __restrict__ W0, const float* __restrict__ W1,
                         const float* __restrict__ em0_w, const float* __restrict__ em1_w,
                         unsigned short* __restrict__ ws)
{
    int id = blockIdx.x * 256 + threadIdx.x;
    if (id >= 261168) return;
    union { __hip_bfloat16 h; unsigned short u; } cv;
    if (id < 12288) {                              // W0p: f = t*3+s, t<8, s<3
        int e = id & 7, l = (id >> 3) & 63, f = id >> 9;
        int g = l >> 4, c = l & 15;
        int s = f % 3, t = f / 3;
        int k = s * 32 + g * 8 + e, n = t * 16 + c;
        float v = (k < 66) ? W0[k * 128 + n]
                : ((k < 68) ? W0[(k - 66) * 128 + n] : 0.0f);
        cv.h = __float2bfloat16(v);
        ws[id] = cv.u;
    } else if (id < 24576) {                       // W1p16 paired
        int id1 = id - 12288;
        int e2 = id1 & 3, h = (id1 >> 2) & 1, l = (id1 >> 3) & 63, p2 = id1 >> 9;
        int g = l >> 4, c = l & 15;
        int q = p2 / 6, t1 = p2 - 6 * q;
        int s1 = 2 * q + h;
        int k = 16 * s1 + 4 * g + e2, n = 16 * t1 + c;
        cv.h = __float2bfloat16(W1[k * 96 + n]);
        ws[id] = cv.u;
    } else if (id < EM1B_OFF) {                    // em0b [6572][24]
        int qd = id - EM0B_OFF;
        int row = qd / 24, col = qd - row * 24;
        cv.h = __float2bfloat16(col < 20 ? em0_w[row * 20 + col] : 0.0f);
        ws[id] = cv.u;
    } else {                                       // em1b [1643][48]
        int qd = id - EM1B_OFF;
        int row = qd / 48, col = qd - row * 48;
        cv.h = __float2bfloat16(col < 44 ? em1_w[row * 44 + col] : 0.0f);
        ws[id] = cv.u;
    }
}

// Swapped-operand MFMA MLP. Layer 0: 16x16x32, D0[out][pt]. Layer 1: 16x16x16,
// whose B-frag (k = 16s1+4g+e) is EXACTLY layer-0's D-quad (out = 16t+4g+r,
// t=s1, e=r) in the SAME lane -> h1 never touches LDS; LDS holds features only.
// __launch_bounds__(64,3): 12 waves/CU (matches 13.3KB-LDS cap), VGPR<=170 so
// pb[8][4]+a0f stay in VGPRs (r8's 68-VGPR alloc forced AGPR round-trips).
__global__ __launch_bounds__(64, 3) void fused_mlp(
    const float* __restrict__ x, const float* __restrict__ emb,
    const float* __restrict__ b0, const float* __restrict__ b1,
    const float* __restrict__ W2, const float* __restrict__ b2,
    const unsigned short* __restrict__ ws,
    float* __restrict__ out, int N)
{
    __shared__ __align__(16) char smem[64 * RSDW * 4];  // 13312 B: features only
    const unsigned short* W0p   = ws;
    const unsigned short* W1p16 = ws + 12288;
    const unsigned short* em0b  = ws + EM0B_OFF;
    const unsigned short* em1b  = ws + EM1B_OFF;

    const int lane = threadIdx.x;                 // one wave per block
    const int g    = lane >> 4, c = lane & 15;
    const int p    = blockIdx.x * 64 + lane;
    const int pc   = min(p, N - 1);

    // ---- Phase A: gather bf16 table regions, lerp, write feature row ------
    // k-layout: [0,1]=bf16(x) [2..21]=em0 [22..65]=em1 [66,67]=x_lo [68..95]=0
    {
        const float t  = emb[pc];
        const int   i0 = (int)t;                  // i0 <= 6570 -> i0+1 valid
        const float pf = t - (float)i0;
        const float t4 = t * 0.25f;               // exact
        const int   j0 = (int)t4;
        int   jbase = j0;  float qf = t4 - (float)j0;
        if (j0 >= E4_TOT - 1) { jbase = E4_TOT - 2; qf = 1.0f; }

        uint4 e0[6];                              // em0b rows i0,i0+1 (96 B)
        const uint4* R0 = (const uint4*)(em0b + i0 * 24);
        #pragma unroll
        for (int v = 0; v < 6; ++v) e0[v] = R0[v];
        uint4 e1[12];                             // em1b rows jbase,jbase+1 (192 B)
        const uint4* R1 = (const uint4*)(em1b + jbase * 48);
        #pragma unroll
        for (int v = 0; v < 12; ++v) e1[v] = R1[v];

        const float2 xv = *(const float2*)(x + 2 * pc);
        union { __hip_bfloat16 h; unsigned short u; } x0, x1;
        x0.h = __float2bfloat16(xv.x);
        x1.h = __float2bfloat16(xv.y);

        unsigned d[48];
        d[0]  = (unsigned)x0.u | ((unsigned)x1.u << 16);
        const unsigned* a0dw = (const unsigned*)e0;     // [0..11] r0, [12..23] r1
        #pragma unroll
        for (int i = 0; i < 10; ++i)
            d[1 + i] = lerp_dw(a0dw[i], a0dw[12 + i], pf);
        const unsigned* b0dw = (const unsigned*)e1;     // [0..23] r0, [24..47] r1
        #pragma unroll
        for (int i = 0; i < 22; ++i)
            d[11 + i] = lerp_dw(b0dw[i], b0dw[24 + i], qf);
        d[33] = pkrn(xv.x - __bfloat162float(x0.h), xv.y - __bfloat162float(x1.h));
        #pragma unroll
        for (int i = 34; i < 48; ++i) d[i] = 0u;

        uint4* rw = (uint4*)(smem + lane * (RSDW * 4));
        #pragma unroll
        for (int ch = 0; ch < 12; ++ch)
            rw[ch] = make_uint4(d[4*ch], d[4*ch+1], d[4*ch+2], d[4*ch+3]);
    }
    // no barrier: all LDS traffic is wave-local; lgkmcnt orders it

    // ---- feature B-frags: lane (g,c) <- feat[k=32s+8g+e][pt=16mt+c] --------
    bf16x8 a0f[4][3];
    #pragma unroll
    for (int mt = 0; mt < 4; ++mt)
        #pragma unroll
        for (int s = 0; s < 3; ++s)
            a0f[mt][s] = *(const bf16x8*)(smem + ((16*mt + c) * RSDW + 16*s + 4*g) * 4);

    // ---- Layer 0 (16x16x32, swapped): D0[out=16t+4g+r][pt=16mt+c] ----------
    // clamp + pack each D-quad -> pb[t][mt] = h1 bf16, ready as L1 B-frags.
    union U2S { uint2 u; bf16x4 s; };
    bf16x4 pb[8][4];
    #pragma unroll
    for (int t = 0; t < 8; ++t) {
        bf16x8 bw[3];
        #pragma unroll
        for (int s = 0; s < 3; ++s)
            bw[s] = *(const bf16x8*)(W0p + ((t*3 + s) << 9) + (lane << 3));
        const float4 b0v = *(const float4*)(b0 + t*16 + g*4);   // b0[16t+4g+r]
        f32x4 acc[4];
        #pragma unroll
        for (int mt = 0; mt < 4; ++mt) acc[mt] = f32x4{b0v.x, b0v.y, b0v.z, b0v.w};
        #pragma unroll
        for (int s = 0; s < 3; ++s)
            #pragma unroll
            for (int mt = 0; mt < 4; ++mt)
                acc[mt] = __builtin_amdgcn_mfma_f32_16x16x32_bf16(bw[s], a0f[mt][s], acc[mt], 0, 0, 0);
        #pragma unroll
        for (int mt = 0; mt < 4; ++mt) {
            U2S u2;
            u2.u = make_uint2(pkrn(clamp01(acc[mt][0]), clamp01(acc[mt][1])),
                              pkrn(clamp01(acc[mt][2]), clamp01(acc[mt][3])));
            pb[t][mt] = u2.s;                     // h1[k=16t+4g+e][pt=16mt+c]
        }
    }

    // ---- Layer 1 (16x16x16, swapped) + fused W2, no LDS --------------------
    float zp[4] = {0.f, 0.f, 0.f, 0.f};
    #pragma unroll
    for (int t1 = 0; t1 < 6; ++t1) {
        const float4 b1v = *(const float4*)(b1 + t1*16 + g*4);  // b1[16t1+4g+r]
        f32x4 acc[4];
        #pragma unroll
        for (int mt = 0; mt < 4; ++mt) acc[mt] = f32x4{b1v.x, b1v.y, b1v.z, b1v.w};
        #pragma unroll
        for (int q = 0; q < 4; ++q) {             // one b128 = frags s1=2q,2q+1
            const bf16x8 pr = *(const bf16x8*)(W1p16 + ((q*6 + t1) << 9) + (lane << 3));
            bf16x4 lo, hi;
            lo[0]=pr[0]; lo[1]=pr[1]; lo[2]=pr[2]; lo[3]=pr[3];
            hi[0]=pr[4]; hi[1]=pr[5]; hi[2]=pr[6]; hi[3]=pr[7];
            #pragma unroll
            for (int mt = 0; mt < 4; ++mt)
                acc[mt] = MFMA16(lo, pb[2*q][mt], acc[mt]);
            #pragma unroll
            for (int mt = 0; mt < 4; ++mt)
                acc[mt] = MFMA16(hi, pb[2*q + 1][mt], acc[mt]);
        }
        const float4 w2v = *(const float4*)(W2 + t1*16 + g*4);  // W2[16t1+4g+r]
        #pragma unroll
        for (int mt = 0; mt < 4; ++mt) {
            zp[mt] = fmaf(clamp01(acc[mt][0]), w2v.x, zp[mt]);
            zp[mt] = fmaf(clamp01(acc[mt][1]), w2v.y, zp[mt]);
            zp[mt] = fmaf(clamp01(acc[mt][2]), w2v.z, zp[mt]);
            zp[mt] = fmaf(clamp01(acc[mt][3]), w2v.w, zp[mt]);
        }
    }

    // ---- reduce over g-groups (4 lanes per pt-column), sigmoid, store ------
    float zr[4];
    #pragma unroll
    for (int mt = 0; mt < 4; ++mt) {
        float v = zp[mt];
        v += __shfl_xor(v, 16);
        v += __shfl_xor(v, 32);
        zr[mt] = v;                               // full z for pt=16mt+c
    }
    float z = (g == 0) ? zr[0] : (g == 1) ? zr[1] : (g == 2) ? zr[2] : zr[3];
    z += b2[0];
    z = 1.0f / (1.0f + __expf(-z));
    if (p < N) out[p] = z;                        // pt = 16g+c = lane: coalesced
}

extern "C" void kernel_launch(void* const* d_in, const int* in_sizes, int n_in,
                              void* d_out, int out_size, void* d_ws, size_t ws_size,
                              hipStream_t stream) {
    const float* x     = (const float*)d_in[0];
    const float* emb   = (const float*)d_in[1];
    const float* em0_w = (const float*)d_in[2];
    const float* em1_w = (const float*)d_in[3];
    const float* W0    = (const float*)d_in[4];
    const float* b0    = (const float*)d_in[5];
    const float* W1    = (const float*)d_in[6];
    const float* b1    = (const float*)d_in[7];
    const float* W2    = (const float*)d_in[8];
    const float* b2    = (const float*)d_in[9];
    float* out = (float*)d_out;
    const int N = in_sizes[1];

    unsigned short* ws = (unsigned short*)d_ws;   // 522336 B used

    pack_all<<<1021, 256, 0, stream>>>(W0, W1, em0_w, em1_w, ws);
    const int nb = (N + 63) / 64;
    fused_mlp<<<nb, 64, 0, stream>>>(x, emb, b0, b1, W2, b2, ws, out, N);
}

// Round 10
// 84.051 us; speedup vs baseline: 2.5938x; 1.0519x over previous
//
#include <hip/hip_runtime.h>
#include <hip/hip_bf16.h>

typedef short bf16x8 __attribute__((ext_vector_type(8)));
typedef short bf16x4 __attribute__((ext_vector_type(4)));
typedef float f32x4  __attribute__((ext_vector_type(4)));

#define E_TOT   6572
#define E4_TOT  1643
#define RSDW    36      // LDS row stride dwords (144 B = 128 B feat + pad); 36%32=4

// d_ws layout (ushort indices):
// [0,8192) W0p (16 frags) | [8192,20480) W1p16 paired |
// [20480,178208) em0b [6572][24] | [178208,257072) em1b [1643][48]
#define W1P_OFF  8192
#define EM0B_OFF 20480
#define EM1B_OFF 178208
#define WS_TOT   257072

#if __has_builtin(__builtin_amdgcn_mfma_f32_16x16x16bf16_1k)
static __device__ __forceinline__ f32x4 MFMA16(bf16x4 a, bf16x4 b, f32x4 c) {
    return __builtin_amdgcn_mfma_f32_16x16x16bf16_1k(a, b, c, 0, 0, 0);
}
#else
static __device__ __forceinline__ f32x4 MFMA16(bf16x4 a, bf16x4 b, f32x4 c) {
    f32x4 d;
    asm volatile("v_mfma_f32_16x16x16_bf16 %0, %1, %2, %3"
                 : "=v"(d) : "v"(a), "v"(b), "v"(c));
    return d;
}
#endif

static __device__ __forceinline__ unsigned pkrn(float a, float b) {
    union { __hip_bfloat162 h; unsigned u; } v;
    v.h = __float22bfloat162_rn(float2{a, b});    // v_cvt_pk_bf16_f32
    return v.u;
}
static __device__ __forceinline__ float clamp01(float v) {
    return __builtin_amdgcn_fmed3f(v, 0.0f, 1.0f);
}
static __device__ __forceinline__ float bperm(int pt, float src) {
    union { float f; int i; } u, r;
    u.f = src;
    r.i = __builtin_amdgcn_ds_bpermute(pt << 2, u.i);
    return r.f;
}
// lerp two packed-bf16 dwords (a=row0, b=row1) with fp32 weight p -> packed bf16
static __device__ __forceinline__ unsigned lerp_dw(unsigned a, unsigned b, float p) {
    float alo = __uint_as_float(a << 16);
    float ahi = __uint_as_float(a & 0xffff0000u);
    float blo = __uint_as_float(b << 16);
    float bhi = __uint_as_float(b & 0xffff0000u);
    return pkrn(fmaf(p, blo - alo, alo), fmaf(p, bhi - ahi, ahi));
}

// W0p: 16x16x32 A-frag order, K=64 (features = em0(20)+em1(44); W0 row = k+2):
//   frag(t,s<2), lane l, elem e  <-  W0[k+2 = 32s+8*(l>>4)+e+2][n = 16t+(l&15)]
// W1p16 (PAIRED x16 A-frags): pair p2 = q*6+t1, lane l, half h, e2<4
//   <- W1[k = 16*(2q+h)+4*(l>>4)+e2][n = 16t1+(l&15)]
// em0b: bf16 [6572][24] (20 cols + pad); em1b: bf16 [1643][48] (44 + pad).
__global__ void pack_all(const float* __restrict__ W0, const float* __restrict__ W1,
                         const float* __restrict__ em0_w, const float* __restrict__ em1_w,
                         unsigned short* __restrict__ ws)
{
    int id = blockIdx.x * 256 + threadIdx.x;
    if (id >= WS_TOT) return;
    union { __hip_bfloat16 h; unsigned short u; } cv;
    if (id < W1P_OFF) {                            // W0p: f = t*2+s, t<8, s<2
        int e = id & 7, l = (id >> 3) & 63, f = id >> 9;
        int g = l >> 4, c = l & 15;
        int s = f & 1, t = f >> 1;
        int k = s * 32 + g * 8 + e, n = t * 16 + c;
        cv.h = __float2bfloat16(W0[(k + 2) * 128 + n]);
        ws[id] = cv.u;
    } else if (id < EM0B_OFF) {                    // W1p16 paired
        int id1 = id - W1P_OFF;
        int e2 = id1 & 3, h = (id1 >> 2) & 1, l = (id1 >> 3) & 63, p2 = id1 >> 9;
        int g = l >> 4, c = l & 15;
        int q = p2 / 6, t1 = p2 - 6 * q;
        int s1 = 2 * q + h;
        int k = 16 * s1 + 4 * g + e2, n = 16 * t1 + c;
        cv.h = __float2bfloat16(W1[k * 96 + n]);
        ws[id] = cv.u;
    } else if (id < EM1B_OFF) {                    // em0b [6572][24]
        int qd = id - EM0B_OFF;
        int row = qd / 24, col = qd - row * 24;
        cv.h = __float2bfloat16(col < 20 ? em0_w[row * 20 + col] : 0.0f);
        ws[id] = cv.u;
    } else {                                       // em1b [1643][48]
        int qd = id - EM1B_OFF;
        int row = qd / 48, col = qd - row * 48;
        cv.h = __float2bfloat16(col < 44 ? em1_w[row * 44 + col] : 0.0f);
        ws[id] = cv.u;
    }
}

// Swapped-operand MFMA MLP, K=64 layer 0 (x handled exactly in fp32 epilogue
// via ds_bpermute); layer 1 = 16x16x16 fed directly from layer-0 D-quads
// (h1 never touches LDS). LDS = 9216 B (features only) -> 17 blocks/CU cap.
__global__ __launch_bounds__(64, 3) void fused_mlp(
    const float* __restrict__ x, const float* __restrict__ emb,
    const float* __restrict__ W0, const float* __restrict__ b0,
    const float* __restrict__ b1,
    const float* __restrict__ W2, const float* __restrict__ b2,
    const unsigned short* __restrict__ ws,
    float* __restrict__ out, int N)
{
    __shared__ __align__(16) char smem[64 * RSDW * 4];  // 9216 B
    const unsigned short* W0p   = ws;
    const unsigned short* W1p16 = ws + W1P_OFF;
    const unsigned short* em0b  = ws + EM0B_OFF;
    const unsigned short* em1b  = ws + EM1B_OFF;

    const int lane = threadIdx.x;                 // one wave per block
    const int g    = lane >> 4, c = lane & 15;
    const int p    = blockIdx.x * 64 + lane;
    const int pc   = min(p, N - 1);

    // ---- Phase A: gather bf16 table regions, lerp, write feature row ------
    // feature k: [0..19]=em0, [20..63]=em1  (x excluded from MFMA)
    float2 xv;
    {
        const float t  = emb[pc];
        const int   i0 = (int)t;                  // i0 <= 6570 -> i0+1 valid
        const float pf = t - (float)i0;
        const float t4 = t * 0.25f;               // exact
        const int   j0 = (int)t4;
        int   jbase = j0;  float qf = t4 - (float)j0;
        if (j0 >= E4_TOT - 1) { jbase = E4_TOT - 2; qf = 1.0f; }

        uint4 e0[6];                              // em0b rows i0,i0+1 (96 B)
        const uint4* R0 = (const uint4*)(em0b + i0 * 24);
        #pragma unroll
        for (int v = 0; v < 6; ++v) e0[v] = R0[v];
        uint4 e1[12];                             // em1b rows jbase,jbase+1 (192 B)
        const uint4* R1 = (const uint4*)(em1b + jbase * 48);
        #pragma unroll
        for (int v = 0; v < 12; ++v) e1[v] = R1[v];

        xv = *(const float2*)(x + 2 * pc);

        unsigned d[32];
        const unsigned* a0dw = (const unsigned*)e0;     // [0..11] r0, [12..23] r1
        #pragma unroll
        for (int i = 0; i < 10; ++i)                    // em0 dims 0..19
            d[i] = lerp_dw(a0dw[i], a0dw[12 + i], pf);
        const unsigned* b0dw = (const unsigned*)e1;     // [0..23] r0, [24..47] r1
        #pragma unroll
        for (int i = 0; i < 22; ++i)                    // em1 dims 0..43
            d[10 + i] = lerp_dw(b0dw[i], b0dw[24 + i], qf);

        uint4* rw = (uint4*)(smem + lane * (RSDW * 4));
        #pragma unroll
        for (int ch = 0; ch < 8; ++ch)
            rw[ch] = make_uint4(d[4*ch], d[4*ch+1], d[4*ch+2], d[4*ch+3]);
    }
    // no barrier: all LDS traffic is wave-local; lgkmcnt orders it

    // ---- x of this lane's column-points via lane exchange ------------------
    float xq0[4], xq1[4];
    #pragma unroll
    for (int mt = 0; mt < 4; ++mt) {
        xq0[mt] = bperm(16*mt + c, xv.x);
        xq1[mt] = bperm(16*mt + c, xv.y);
    }

    // ---- feature B-frags: lane (g,c) <- feat[k=32s+8g+e][pt=16mt+c] --------
    bf16x8 a0f[4][2];
    #pragma unroll
    for (int mt = 0; mt < 4; ++mt)
        #pragma unroll
        for (int s = 0; s < 2; ++s)
            a0f[mt][s] = *(const bf16x8*)(smem + ((16*mt + c) * RSDW) * 4 + 64*s + 16*g);

    // ---- Layer 0 (16x16x32, K=64, swapped): D0[out=16t+4g+r][pt=16mt+c] ----
    // epilogue adds exact fp32 x-contribution, clamps, packs -> L1 B-frags.
    union U2S { uint2 u; bf16x4 s; };
    bf16x4 pb[8][4];
    #pragma unroll
    for (int t = 0; t < 8; ++t) {
        bf16x8 bw[2];
        #pragma unroll
        for (int s = 0; s < 2; ++s)
            bw[s] = *(const bf16x8*)(W0p + ((t*2 + s) << 9) + (lane << 3));
        const float4 b0v = *(const float4*)(b0 + t*16 + g*4);   // b0[16t+4g+r]
        f32x4 acc[4];
        #pragma unroll
        for (int mt = 0; mt < 4; ++mt) acc[mt] = f32x4{b0v.x, b0v.y, b0v.z, b0v.w};
        #pragma unroll
        for (int s = 0; s < 2; ++s)
            #pragma unroll
            for (int mt = 0; mt < 4; ++mt)
                acc[mt] = __builtin_amdgcn_mfma_f32_16x16x32_bf16(bw[s], a0f[mt][s], acc[mt], 0, 0, 0);
        const float4 wa = *(const float4*)(W0 + t*16 + g*4);        // W0[0][n]
        const float4 wb = *(const float4*)(W0 + 128 + t*16 + g*4);  // W0[1][n]
        const float wa_[4] = {wa.x, wa.y, wa.z, wa.w};
        const float wb_[4] = {wb.x, wb.y, wb.z, wb.w};
        #pragma unroll
        for (int mt = 0; mt < 4; ++mt) {
            float v0 = clamp01(fmaf(xq0[mt], wa_[0], fmaf(xq1[mt], wb_[0], acc[mt][0])));
            float v1 = clamp01(fmaf(xq0[mt], wa_[1], fmaf(xq1[mt], wb_[1], acc[mt][1])));
            float v2 = clamp01(fmaf(xq0[mt], wa_[2], fmaf(xq1[mt], wb_[2], acc[mt][2])));
            float v3 = clamp01(fmaf(xq0[mt], wa_[3], fmaf(xq1[mt], wb_[3], acc[mt][3])));
            U2S u2;
            u2.u = make_uint2(pkrn(v0, v1), pkrn(v2, v3));
            pb[t][mt] = u2.s;                     // h1[k=16t+4g+e][pt=16mt+c]
        }
    }

    // ---- Layer 1 (16x16x16, swapped) + fused W2, no LDS --------------------
    float zp[4] = {0.f, 0.f, 0.f, 0.f};
    #pragma unroll
    for (int t1 = 0; t1 < 6; ++t1) {
        const float4 b1v = *(const float4*)(b1 + t1*16 + g*4);  // b1[16t1+4g+r]
        f32x4 acc[4];
        #pragma unroll
        for (int mt = 0; mt < 4; ++mt) acc[mt] = f32x4{b1v.x, b1v.y, b1v.z, b1v.w};
        #pragma unroll
        for (int q = 0; q < 4; ++q) {             // one b128 = frags s1=2q,2q+1
            const bf16x8 pr = *(const bf16x8*)(W1p16 + ((q*6 + t1) << 9) + (lane << 3));
            bf16x4 lo, hi;
            lo[0]=pr[0]; lo[1]=pr[1]; lo[2]=pr[2]; lo[3]=pr[3];
            hi[0]=pr[4]; hi[1]=pr[5]; hi[2]=pr[6]; hi[3]=pr[7];
            #pragma unroll
            for (int mt = 0; mt < 4; ++mt)
                acc[mt] = MFMA16(lo, pb[2*q][mt], acc[mt]);
            #pragma unroll
            for (int mt = 0; mt < 4; ++mt)
                acc[mt] = MFMA16(hi, pb[2*q + 1][mt], acc[mt]);
        }
        const float4 w2v = *(const float4*)(W2 + t1*16 + g*4);  // W2[16t1+4g+r]
        #pragma unroll
        for (int mt = 0; mt < 4; ++mt) {
            zp[mt] = fmaf(clamp01(acc[mt][0]), w2v.x, zp[mt]);
            zp[mt] = fmaf(clamp01(acc[mt][1]), w2v.y, zp[mt]);
            zp[mt] = fmaf(clamp01(acc[mt][2]), w2v.z, zp[mt]);
            zp[mt] = fmaf(clamp01(acc[mt][3]), w2v.w, zp[mt]);
        }
    }

    // ---- reduce over g-groups (4 lanes per pt-column), sigmoid, store ------
    float zr[4];
    #pragma unroll
    for (int mt = 0; mt < 4; ++mt) {
        float v = zp[mt];
        v += __shfl_xor(v, 16);
        v += __shfl_xor(v, 32);
        zr[mt] = v;                               // full z for pt=16mt+c
    }
    float z = (g == 0) ? zr[0] : (g == 1) ? zr[1] : (g == 2) ? zr[2] : zr[3];
    z += b2[0];
    z = 1.0f / (1.0f + __expf(-z));
    if (p < N) out[p] = z;                        // pt = 16g+c = lane: coalesced
}

extern "C" void kernel_launch(void* const* d_in, const int* in_sizes, int n_in,
                              void* d_out, int out_size, void* d_ws, size_t ws_size,
                              hipStream_t stream) {
    const float* x     = (const float*)d_in[0];
    const float* emb   = (const float*)d_in[1];
    const float* em0_w = (const float*)d_in[2];
    const float* em1_w = (const float*)d_in[3];
    const float* W0    = (const float*)d_in[4];
    const float* b0    = (const float*)d_in[5];
    const float* W1    = (const float*)d_in[6];
    const float* b1    = (const float*)d_in[7];
    const float* W2    = (const float*)d_in[8];
    const float* b2    = (const float*)d_in[9];
    float* out = (float*)d_out;
    const int N = in_sizes[1];

    unsigned short* ws = (unsigned short*)d_ws;   // 514144 B used

    pack_all<<<(WS_TOT + 255) / 256, 256, 0, stream>>>(W0, W1, em0_w, em1_w, ws);
    const int nb = (N + 63) / 64;
    fused_mlp<<<nb, 64, 0, stream>>>(x, emb, W0, b0, b1, W2, b2, ws, out, N);
}

// Round 13
// 81.036 us; speedup vs baseline: 2.6903x; 1.0372x over previous
//
#include <hip/hip_runtime.h>
#include <hip/hip_bf16.h>

typedef _Float16 f16x8 __attribute__((ext_vector_type(8)));
typedef _Float16 f16x4 __attribute__((ext_vector_type(4)));
typedef _Float16 f16x2 __attribute__((ext_vector_type(2)));
typedef __fp16   fp16v2 __attribute__((ext_vector_type(2)));   // builtin's return type
typedef float    f32x4 __attribute__((ext_vector_type(4)));

#define E_TOT   6572
#define E4_TOT  1643
#define RSDW    36      // LDS row stride dwords (144 B = 128 B feat + pad); 36%32=4

// d_ws layout (ushort indices):
// [0,8192) W0p (16 frags) | [8192,20480) W1p16 paired |
// [20480,178208) em0h [6572][24] | [178208,257072) em1h [1643][48]   (all fp16)
#define W1P_OFF  8192
#define EM0B_OFF 20480
#define EM1B_OFF 178208
#define WS_TOT   257072

#if __has_builtin(__builtin_amdgcn_mfma_f32_16x16x16f16)
static __device__ __forceinline__ f32x4 MFMA16(f16x4 a, f16x4 b, f32x4 c) {
    return __builtin_amdgcn_mfma_f32_16x16x16f16(a, b, c, 0, 0, 0);
}
#else
static __device__ __forceinline__ f32x4 MFMA16(f16x4 a, f16x4 b, f32x4 c) {
    asm volatile("v_mfma_f32_16x16x16_f16 %0, %1, %2, %0"
                 : "+v"(c) : "v"(a), "v"(b));
    return c;
}
#endif

static __device__ __forceinline__ float clamp01(float v) {
    return __builtin_amdgcn_fmed3f(v, 0.0f, 1.0f);
}
// clamp(x,0,1) in fp32 (fmed3), then packed convert to f16 (RTZ).
// (r11 fused the clamp into the cvt's VOP3 clamp bit -> absmax 0.117: that
// modifier does NOT implement [0,1] saturation on both packed halves.)
static __device__ __forceinline__ unsigned cvt_pk_c01(float lo, float hi) {
    union { fp16v2 h; unsigned u; } r;
    r.h = __builtin_amdgcn_cvt_pkrtz(clamp01(lo), clamp01(hi));
    return r.u;
}
// packed-f16 lerp of one dword (2 elems): 2 VALU ops (v_pk_add + v_pk_fma)
static __device__ __forceinline__ unsigned lerp_h2(unsigned a, unsigned b, f16x2 p2) {
    union { unsigned u; f16x2 h; } A, B, R;
    A.u = a; B.u = b;
    R.h = A.h + p2 * (B.h - A.h);
    return R.u;
}

// W0p: 16x16x32 f16 A-frag order, K=64 (features = em0(20)+em1(44); W0 row = k+2):
//   frag(t,s<2), lane l, elem e  <-  W0[k+2][n = 16t+(l&15)], k = 32s+8*(l>>4)+e
// W1p16 (PAIRED x16 A-frags): pair p2 = q*6+t1, lane l, half h, e2<4
//   <- W1[k = 16*(2q+h)+4*(l>>4)+e2][n = 16t1+(l&15)]
// em0h: f16 [6572][24] (20 cols + pad); em1h: f16 [1643][48] (44 + pad).
__global__ void pack_all(const float* __restrict__ W0, const float* __restrict__ W1,
                         const float* __restrict__ em0_w, const float* __restrict__ em1_w,
                         unsigned short* __restrict__ ws)
{
    int id = blockIdx.x * 256 + threadIdx.x;
    if (id >= WS_TOT) return;
    union { _Float16 h; unsigned short u; } cv;
    if (id < W1P_OFF) {                            // W0p: f = t*2+s, t<8, s<2
        int e = id & 7, l = (id >> 3) & 63, f = id >> 9;
        int g = l >> 4, c = l & 15;
        int s = f & 1, t = f >> 1;
        int k = s * 32 + g * 8 + e, n = t * 16 + c;
        cv.h = (_Float16)W0[(k + 2) * 128 + n];
        ws[id] = cv.u;
    } else if (id < EM0B_OFF) {                    // W1p16 paired
        int id1 = id - W1P_OFF;
        int e2 = id1 & 3, h = (id1 >> 2) & 1, l = (id1 >> 3) & 63, p2 = id1 >> 9;
        int g = l >> 4, c = l & 15;
        int q = p2 / 6, t1 = p2 - 6 * q;
        int s1 = 2 * q + h;
        int k = 16 * s1 + 4 * g + e2, n = 16 * t1 + c;
        cv.h = (_Float16)W1[k * 96 + n];
        ws[id] = cv.u;
    } else if (id < EM1B_OFF) {                    // em0h [6572][24]
        int qd = id - EM0B_OFF;
        int row = qd / 24, col = qd - row * 24;
        cv.h = (_Float16)(col < 20 ? em0_w[row * 20 + col] : 0.0f);
        ws[id] = cv.u;
    } else {                                       // em1h [1643][48]
        int qd = id - EM1B_OFF;
        int row = qd / 48, col = qd - row * 48;
        cv.h = (_Float16)(col < 44 ? em1_w[row * 44 + col] : 0.0f);
        ws[id] = cv.u;
    }
}

// Swapped-operand f16 MFMA MLP, K=64 layer 0 (x handled exactly in fp32
// epilogue via ds_bpermute); layer 1 = 16x16x16 fed directly from layer-0
// D-quads (h1 never touches LDS). LDS = 9216 B (features only).
__global__ __launch_bounds__(64, 3) void fused_mlp(
    const float* __restrict__ x, const float* __restrict__ emb,
    const float* __restrict__ W0, const float* __restrict__ b0,
    const float* __restrict__ b1,
    const float* __restrict__ W2, const float* __restrict__ b2,
    const unsigned short* __restrict__ ws,
    float* __restrict__ out, int N)
{
    __shared__ __align__(16) char smem[64 * RSDW * 4];  // 9216 B
    const unsigned short* W0p   = ws;
    const unsigned short* W1p16 = ws + W1P_OFF;
    const unsigned short* em0h  = ws + EM0B_OFF;
    const unsigned short* em1h  = ws + EM1B_OFF;

    const int lane = threadIdx.x;                 // one wave per block
    const int g    = lane >> 4, c = lane & 15;
    const int p    = blockIdx.x * 64 + lane;
    const int pc   = min(p, N - 1);

    // ---- Phase A: gather f16 table regions, packed-f16 lerp, write row ----
    // feature k: [0..19]=em0, [20..63]=em1  (x excluded from MFMA)
    float2 xv;
    {
        const float t  = emb[pc];
        const int   i0 = (int)t;                  // i0 <= 6570 -> i0+1 valid
        const float pf = t - (float)i0;
        const float t4 = t * 0.25f;               // exact
        const int   j0 = (int)t4;
        int   jbase = j0;  float qf = t4 - (float)j0;
        if (j0 >= E4_TOT - 1) { jbase = E4_TOT - 2; qf = 1.0f; }

        uint4 e0[6];                              // em0h rows i0,i0+1 (96 B)
        const uint4* R0 = (const uint4*)(em0h + i0 * 24);
        #pragma unroll
        for (int v = 0; v < 6; ++v) e0[v] = R0[v];
        uint4 e1[12];                             // em1h rows jbase,jbase+1 (192 B)
        const uint4* R1 = (const uint4*)(em1h + jbase * 48);
        #pragma unroll
        for (int v = 0; v < 12; ++v) e1[v] = R1[v];

        xv = *(const float2*)(x + 2 * pc);

        const f16x2 pf2 = {(_Float16)pf, (_Float16)pf};
        const f16x2 qf2 = {(_Float16)qf, (_Float16)qf};

        unsigned d[32];
        const unsigned* a0dw = (const unsigned*)e0;     // [0..11] r0, [12..23] r1
        #pragma unroll
        for (int i = 0; i < 10; ++i)                    // em0 dims 0..19
            d[i] = lerp_h2(a0dw[i], a0dw[12 + i], pf2);
        const unsigned* b0dw = (const unsigned*)e1;     // [0..23] r0, [24..47] r1
        #pragma unroll
        for (int i = 0; i < 22; ++i)                    // em1 dims 0..43
            d[10 + i] = lerp_h2(b0dw[i], b0dw[24 + i], qf2);

        uint4* rw = (uint4*)(smem + lane * (RSDW * 4));
        #pragma unroll
        for (int ch = 0; ch < 8; ++ch)
            rw[ch] = make_uint4(d[4*ch], d[4*ch+1], d[4*ch+2], d[4*ch+3]);
    }
    // no barrier: all LDS traffic is wave-local; lgkmcnt orders it

    // ---- x of this lane's column-points via lane exchange ------------------
    float xq0[4], xq1[4];
    #pragma unroll
    for (int mt = 0; mt < 4; ++mt) {
        union { float f; int i; } ux, rx, uy, ry;
        ux.f = xv.x; uy.f = xv.y;
        rx.i = __builtin_amdgcn_ds_bpermute((16*mt + c) << 2, ux.i);
        ry.i = __builtin_amdgcn_ds_bpermute((16*mt + c) << 2, uy.i);
        xq0[mt] = rx.f; xq1[mt] = ry.f;
    }

    // ---- feature B-frags: lane (g,c) <- feat[k=32s+8g+e][pt=16mt+c] --------
    f16x8 a0f[4][2];
    #pragma unroll
    for (int mt = 0; mt < 4; ++mt)
        #pragma unroll
        for (int s = 0; s < 2; ++s)
            a0f[mt][s] = *(const f16x8*)(smem + ((16*mt + c) * RSDW) * 4 + 64*s + 16*g);

    // ---- Layer 0 (16x16x32 f16, K=64, swapped): D0[out=16t+4g+r][pt=16mt+c] -
    // epilogue adds exact fp32 x-contribution, fmed3-clamps, packs -> L1 frags
    union U2S { uint2 u; f16x4 s; };
    f16x4 pb[8][4];
    #pragma unroll
    for (int t = 0; t < 8; ++t) {
        f16x8 bw[2];
        #pragma unroll
        for (int s = 0; s < 2; ++s)
            bw[s] = *(const f16x8*)(W0p + ((t*2 + s) << 9) + (lane << 3));
        const float4 b0v = *(const float4*)(b0 + t*16 + g*4);   // b0[16t+4g+r]
        f32x4 acc[4];
        #pragma unroll
        for (int mt = 0; mt < 4; ++mt) acc[mt] = f32x4{b0v.x, b0v.y, b0v.z, b0v.w};
        #pragma unroll
        for (int s = 0; s < 2; ++s)
            #pragma unroll
            for (int mt = 0; mt < 4; ++mt)
                acc[mt] = __builtin_amdgcn_mfma_f32_16x16x32_f16(bw[s], a0f[mt][s], acc[mt], 0, 0, 0);
        const float4 wa = *(const float4*)(W0 + t*16 + g*4);        // W0[0][n]
        const float4 wb = *(const float4*)(W0 + 128 + t*16 + g*4);  // W0[1][n]
        const float wa_[4] = {wa.x, wa.y, wa.z, wa.w};
        const float wb_[4] = {wb.x, wb.y, wb.z, wb.w};
        #pragma unroll
        for (int mt = 0; mt < 4; ++mt) {
            float v0 = fmaf(xq0[mt], wa_[0], fmaf(xq1[mt], wb_[0], acc[mt][0]));
            float v1 = fmaf(xq0[mt], wa_[1], fmaf(xq1[mt], wb_[1], acc[mt][1]));
            float v2 = fmaf(xq0[mt], wa_[2], fmaf(xq1[mt], wb_[2], acc[mt][2]));
            float v3 = fmaf(xq0[mt], wa_[3], fmaf(xq1[mt], wb_[3], acc[mt][3]));
            U2S u2;
            u2.u = make_uint2(cvt_pk_c01(v0, v1), cvt_pk_c01(v2, v3));
            pb[t][mt] = u2.s;                     // h1[k=16t+4g+e][pt=16mt+c]
        }
    }

    // ---- Layer 1 (16x16x16 f16, swapped) + fused W2, no LDS ----------------
    float zp[4] = {0.f, 0.f, 0.f, 0.f};
    #pragma unroll
    for (int t1 = 0; t1 < 6; ++t1) {
        const float4 b1v = *(const float4*)(b1 + t1*16 + g*4);  // b1[16t1+4g+r]
        f32x4 acc[4];
        #pragma unroll
        for (int mt = 0; mt < 4; ++mt) acc[mt] = f32x4{b1v.x, b1v.y, b1v.z, b1v.w};
        #pragma unroll
        for (int q = 0; q < 4; ++q) {             // one b128 = frags s1=2q,2q+1
            const f16x8 pr = *(const f16x8*)(W1p16 + ((q*6 + t1) << 9) + (lane << 3));
            f16x4 lo, hi;
            lo[0]=pr[0]; lo[1]=pr[1]; lo[2]=pr[2]; lo[3]=pr[3];
            hi[0]=pr[4]; hi[1]=pr[5]; hi[2]=pr[6]; hi[3]=pr[7];
            #pragma unroll
            for (int mt = 0; mt < 4; ++mt)
                acc[mt] = MFMA16(lo, pb[2*q][mt], acc[mt]);
            #pragma unroll
            for (int mt = 0; mt < 4; ++mt)
                acc[mt] = MFMA16(hi, pb[2*q + 1][mt], acc[mt]);
        }
        const float4 w2v = *(const float4*)(W2 + t1*16 + g*4);  // W2[16t1+4g+r]
        #pragma unroll
        for (int mt = 0; mt < 4; ++mt) {
            zp[mt] = fmaf(clamp01(acc[mt][0]), w2v.x, zp[mt]);
            zp[mt] = fmaf(clamp01(acc[mt][1]), w2v.y, zp[mt]);
            zp[mt] = fmaf(clamp01(acc[mt][2]), w2v.z, zp[mt]);
            zp[mt] = fmaf(clamp01(acc[mt][3]), w2v.w, zp[mt]);
        }
    }

    // ---- reduce over g-groups (4 lanes per pt-column), sigmoid, store ------
    float zr[4];
    #pragma unroll
    for (int mt = 0; mt < 4; ++mt) {
        float v = zp[mt];
        v += __shfl_xor(v, 16);
        v += __shfl_xor(v, 32);
        zr[mt] = v;                               // full z for pt=16mt+c
    }
    float z = (g == 0) ? zr[0] : (g == 1) ? zr[1] : (g == 2) ? zr[2] : zr[3];
    z += b2[0];
    z = 1.0f / (1.0f + __expf(-z));
    if (p < N) out[p] = z;                        // pt = 16g+c = lane: coalesced
}

extern "C" void kernel_launch(void* const* d_in, const int* in_sizes, int n_in,
                              void* d_out, int out_size, void* d_ws, size_t ws_size,
                              hipStream_t stream) {
    const float* x     = (const float*)d_in[0];
    const float* emb   = (const float*)d_in[1];
    const float* em0_w = (const float*)d_in[2];
    const float* em1_w = (const float*)d_in[3];
    const float* W0    = (const float*)d_in[4];
    const float* b0    = (const float*)d_in[5];
    const float* W1    = (const float*)d_in[6];
    const float* b1    = (const float*)d_in[7];
    const float* W2    = (const float*)d_in[8];
    const float* b2    = (const float*)d_in[9];
    float* out = (float*)d_out;
    const int N = in_sizes[1];

    unsigned short* ws = (unsigned short*)d_ws;   // 514144 B used

    pack_all<<<(WS_TOT + 255) / 256, 256, 0, stream>>>(W0, W1, em0_w, em1_w, ws);
    const int nb = (N + 63) / 64;
    fused_mlp<<<nb, 64, 0, stream>>>(x, emb, W0, b0, b1, W2, b2, ws, out, N);
}

// Round 14
// 77.269 us; speedup vs baseline: 2.8215x; 1.0488x over previous
//
#include <hip/hip_runtime.h>
#include <hip/hip_bf16.h>

typedef _Float16 f16x8 __attribute__((ext_vector_type(8)));
typedef _Float16 f16x4 __attribute__((ext_vector_type(4)));
typedef _Float16 f16x2 __attribute__((ext_vector_type(2)));
typedef __fp16   fp16v2 __attribute__((ext_vector_type(2)));   // cvt_pkrtz return type
typedef float    f32x4 __attribute__((ext_vector_type(4)));

#define E_TOT   6572
#define E4_TOT  1643
#define RSDW    36      // LDS row stride dwords (144 B = 128 B feat + pad); 36%32=4

// d_ws layout (ushort indices):
// [0,8192) W0p (16 frags) | [8192,20480) W1p16 paired |
// [20480,178208) em0h [6572][24] | [178208,257072) em1h [1643][48]   (all fp16)
#define W1P_OFF  8192
#define EM0B_OFF 20480
#define EM1B_OFF 178208
#define WS_TOT   257072

#if __has_builtin(__builtin_amdgcn_mfma_f32_16x16x16f16)
static __device__ __forceinline__ f32x4 MFMA16(f16x4 a, f16x4 b, f32x4 c) {
    return __builtin_amdgcn_mfma_f32_16x16x16f16(a, b, c, 0, 0, 0);
}
#else
static __device__ __forceinline__ f32x4 MFMA16(f16x4 a, f16x4 b, f32x4 c) {
    asm volatile("v_mfma_f32_16x16x16_f16 %0, %1, %2, %0"
                 : "+v"(c) : "v"(a), "v"(b));
    return c;
}
#endif

static __device__ __forceinline__ float clamp01(float v) {
    return __builtin_amdgcn_fmed3f(v, 0.0f, 1.0f);
}
static __device__ __forceinline__ unsigned cvt_pk_c01(float lo, float hi) {
    union { fp16v2 h; unsigned u; } r;
    r.h = __builtin_amdgcn_cvt_pkrtz(clamp01(lo), clamp01(hi));
    return r.u;
}
// packed-f16 lerp of one dword (2 elems): 2 VALU ops (v_pk_add + v_pk_fma)
static __device__ __forceinline__ unsigned lerp_h2(unsigned a, unsigned b, f16x2 p2) {
    union { unsigned u; f16x2 h; } A, B, R;
    A.u = a; B.u = b;
    R.h = A.h + p2 * (B.h - A.h);
    return R.u;
}
static __device__ __forceinline__ int bperm_i(int pt, int v) {
    return __builtin_amdgcn_ds_bpermute(pt << 2, v);
}
static __device__ __forceinline__ float bperm_f(int pt, float v) {
    union { float f; int i; } u, r;
    u.f = v;
    r.i = __builtin_amdgcn_ds_bpermute(pt << 2, u.i);
    return r.f;
}

// Feature k-order (PERMUTED for aligned cooperative writes):
//   k 0..43  = em1 col k      (W0 row 22+k)
//   k 44..63 = em0 col (k-44) (W0 row k-42)
// W0p: 16x16x32 f16 A-frag order, K=64:
//   frag(t,s<2), lane l, elem e <- W0[wrow(k)][n=16t+(l&15)], k = 32s+8*(l>>4)+e
// W1p16 (PAIRED x16 A-frags): pair p2 = q*6+t1, lane l, half h, e2<4
//   <- W1[k = 16*(2q+h)+4*(l>>4)+e2][n = 16t1+(l&15)]
// em0h: f16 [6572][24] (20 cols + 4 zero-pad); em1h: f16 [1643][48] (44 + 4 pad).
__global__ void pack_all(const float* __restrict__ W0, const float* __restrict__ W1,
                         const float* __restrict__ em0_w, const float* __restrict__ em1_w,
                         unsigned short* __restrict__ ws)
{
    int id = blockIdx.x * 256 + threadIdx.x;
    if (id >= WS_TOT) return;
    union { _Float16 h; unsigned short u; } cv;
    if (id < W1P_OFF) {                            // W0p: f = t*2+s, t<8, s<2
        int e = id & 7, l = (id >> 3) & 63, f = id >> 9;
        int g = l >> 4, c = l & 15;
        int s = f & 1, t = f >> 1;
        int k = s * 32 + g * 8 + e, n = t * 16 + c;
        int wrow = (k < 44) ? (22 + k) : (k - 42);  // em1-first permuted order
        cv.h = (_Float16)W0[wrow * 128 + n];
        ws[id] = cv.u;
    } else if (id < EM0B_OFF) {                    // W1p16 paired
        int id1 = id - W1P_OFF;
        int e2 = id1 & 3, h = (id1 >> 2) & 1, l = (id1 >> 3) & 63, p2 = id1 >> 9;
        int g = l >> 4, c = l & 15;
        int q = p2 / 6, t1 = p2 - 6 * q;
        int s1 = 2 * q + h;
        int k = 16 * s1 + 4 * g + e2, n = 16 * t1 + c;
        cv.h = (_Float16)W1[k * 96 + n];
        ws[id] = cv.u;
    } else if (id < EM1B_OFF) {                    // em0h [6572][24]
        int qd = id - EM0B_OFF;
        int row = qd / 24, col = qd - row * 24;
        cv.h = (_Float16)(col < 20 ? em0_w[row * 20 + col] : 0.0f);
        ws[id] = cv.u;
    } else {                                       // em1h [1643][48]
        int qd = id - EM1B_OFF;
        int row = qd / 48, col = qd - row * 48;
        cv.h = (_Float16)(col < 44 ? em1_w[row * 44 + col] : 0.0f);
        ws[id] = cv.u;
    }
}

// Swapped-operand f16 MFMA MLP, K=64 layer 0 (x exact-fp32 in epilogue);
// layer 1 = 16x16x16 fed from layer-0 D-quads (h1 never touches LDS).
// Phase A uses COOPERATIVE gathers: lanes split into (point,chunk) slots so
// each global-load instr touches ~16-24 cache lines instead of 64.
__global__ __launch_bounds__(64, 3) void fused_mlp(
    const float* __restrict__ x, const float* __restrict__ emb,
    const float* __restrict__ W0, const float* __restrict__ b0,
    const float* __restrict__ b1,
    const float* __restrict__ W2, const float* __restrict__ b2,
    const unsigned short* __restrict__ ws,
    float* __restrict__ out, int N)
{
    __shared__ __align__(16) char smem[64 * RSDW * 4];  // 9216 B (features only)
    const unsigned short* W0p   = ws;
    const unsigned short* W1p16 = ws + W1P_OFF;
    const unsigned short* em0h  = ws + EM0B_OFF;
    const unsigned short* em1h  = ws + EM1B_OFF;

    const int lane = threadIdx.x;                 // one wave per block
    const int g    = lane >> 4, c = lane & 15;
    const int p    = blockIdx.x * 64 + lane;
    const int pc   = min(p, N - 1);

    // ---- own-point params ---------------------------------------------------
    const float t  = emb[pc];
    const int   i0 = (int)t;                      // i0 <= 6570 -> i0+1 valid
    const float pf = t - (float)i0;
    const float t4 = t * 0.25f;                   // exact
    const int   j0 = (int)t4;
    int   jb = j0;  float qf = t4 - (float)j0;
    if (j0 >= E4_TOT - 1) { jb = E4_TOT - 2; qf = 1.0f; }
    const float2 xv = *(const float2*)(x + 2 * pc);

    // ---- Phase A: COOPERATIVE gather+lerp -> feature rows -------------------
    // em1 (44 cols): 6 x 16B chunks/pt; slot G = it*64+lane -> pt=G/6, j=G%6.
    // dest feat bytes 16j (k = 8j..8j+7); j=5's cols 44-47 are zero-pad,
    // overwritten below by em0. Raw pair region is 192B contiguous.
    #pragma unroll
    for (int it = 0; it < 6; ++it) {
        const int Gx = it * 64 + lane;            // [0,384)
        const int pt = Gx / 6, j = Gx - pt * 6;
        const int   jbp = bperm_i(pt, jb);
        const float qfp = bperm_f(pt, qf);
        const unsigned short* base = em1h + jbp * 48 + j * 8;
        const uint4 r0 = *(const uint4*)(base);
        const uint4 r1 = *(const uint4*)(base + 48);
        const f16x2 q2 = {(_Float16)qfp, (_Float16)qfp};
        *(uint4*)(smem + pt * (RSDW * 4) + j * 16) =
            make_uint4(lerp_h2(r0.x, r1.x, q2), lerp_h2(r0.y, r1.y, q2),
                       lerp_h2(r0.z, r1.z, q2), lerp_h2(r0.w, r1.w, q2));
    }
    // em0 (20 cols): 5 x 8B chunks/pt; slot G = it*64+lane -> pt=G/5, j=G%5.
    // dest feat bytes 88+8j (k = 44+4j..47+4j). Runs AFTER em1 (program order)
    // so it overwrites em1's j=5 pad bytes 88-95 with real data.
    #pragma unroll
    for (int it = 0; it < 5; ++it) {
        const int Gx = it * 64 + lane;            // [0,320)
        const int pt = Gx / 5, j = Gx - pt * 5;
        const int   i0p = bperm_i(pt, i0);
        const float pfp = bperm_f(pt, pf);
        const unsigned short* base = em0h + i0p * 24 + j * 4;
        const uint2 r0 = *(const uint2*)(base);
        const uint2 r1 = *(const uint2*)(base + 24);
        const f16x2 p2 = {(_Float16)pfp, (_Float16)pfp};
        *(uint2*)(smem + pt * (RSDW * 4) + 88 + j * 8) =
            make_uint2(lerp_h2(r0.x, r1.x, p2), lerp_h2(r0.y, r1.y, p2));
    }
    // no barrier: single wave; LDS ops issue in program order (same as r5-r13)

    // ---- x of this lane's column-points via lane exchange ------------------
    float xq0[4], xq1[4];
    #pragma unroll
    for (int mt = 0; mt < 4; ++mt) {
        xq0[mt] = bperm_f(16*mt + c, xv.x);
        xq1[mt] = bperm_f(16*mt + c, xv.y);
    }

    // ---- feature B-frags: lane (g,c) <- feat[k=32s+8g+e][pt=16mt+c] --------
    f16x8 a0f[4][2];
    #pragma unroll
    for (int mt = 0; mt < 4; ++mt)
        #pragma unroll
        for (int s = 0; s < 2; ++s)
            a0f[mt][s] = *(const f16x8*)(smem + ((16*mt + c) * RSDW) * 4 + 64*s + 16*g);

    // ---- Layer 0 (16x16x32 f16, K=64, swapped): D0[out=16t+4g+r][pt=16mt+c] -
    // epilogue adds exact fp32 x-contribution, fmed3-clamps, packs -> L1 frags
    union U2S { uint2 u; f16x4 s; };
    f16x4 pb[8][4];
    #pragma unroll
    for (int tt = 0; tt < 8; ++tt) {
        f16x8 bw[2];
        #pragma unroll
        for (int s = 0; s < 2; ++s)
            bw[s] = *(const f16x8*)(W0p + ((tt*2 + s) << 9) + (lane << 3));
        const float4 b0v = *(const float4*)(b0 + tt*16 + g*4);  // b0[16t+4g+r]
        f32x4 acc[4];
        #pragma unroll
        for (int mt = 0; mt < 4; ++mt) acc[mt] = f32x4{b0v.x, b0v.y, b0v.z, b0v.w};
        #pragma unroll
        for (int s = 0; s < 2; ++s)
            #pragma unroll
            for (int mt = 0; mt < 4; ++mt)
                acc[mt] = __builtin_amdgcn_mfma_f32_16x16x32_f16(bw[s], a0f[mt][s], acc[mt], 0, 0, 0);
        const float4 wa = *(const float4*)(W0 + tt*16 + g*4);        // W0[0][n]
        const float4 wb = *(const float4*)(W0 + 128 + tt*16 + g*4);  // W0[1][n]
        const float wa_[4] = {wa.x, wa.y, wa.z, wa.w};
        const float wb_[4] = {wb.x, wb.y, wb.z, wb.w};
        #pragma unroll
        for (int mt = 0; mt < 4; ++mt) {
            float v0 = fmaf(xq0[mt], wa_[0], fmaf(xq1[mt], wb_[0], acc[mt][0]));
            float v1 = fmaf(xq0[mt], wa_[1], fmaf(xq1[mt], wb_[1], acc[mt][1]));
            float v2 = fmaf(xq0[mt], wa_[2], fmaf(xq1[mt], wb_[2], acc[mt][2]));
            float v3 = fmaf(xq0[mt], wa_[3], fmaf(xq1[mt], wb_[3], acc[mt][3]));
            U2S u2;
            u2.u = make_uint2(cvt_pk_c01(v0, v1), cvt_pk_c01(v2, v3));
            pb[tt][mt] = u2.s;                    // h1[k=16t+4g+e][pt=16mt+c]
        }
    }

    // ---- Layer 1 (16x16x16 f16, swapped) + fused W2, no LDS ----------------
    float zp[4] = {0.f, 0.f, 0.f, 0.f};
    #pragma unroll
    for (int t1 = 0; t1 < 6; ++t1) {
        const float4 b1v = *(const float4*)(b1 + t1*16 + g*4);  // b1[16t1+4g+r]
        f32x4 acc[4];
        #pragma unroll
        for (int mt = 0; mt < 4; ++mt) acc[mt] = f32x4{b1v.x, b1v.y, b1v.z, b1v.w};
        #pragma unroll
        for (int q = 0; q < 4; ++q) {             // one b128 = frags s1=2q,2q+1
            const f16x8 pr = *(const f16x8*)(W1p16 + ((q*6 + t1) << 9) + (lane << 3));
            f16x4 lo, hi;
            lo[0]=pr[0]; lo[1]=pr[1]; lo[2]=pr[2]; lo[3]=pr[3];
            hi[0]=pr[4]; hi[1]=pr[5]; hi[2]=pr[6]; hi[3]=pr[7];
            #pragma unroll
            for (int mt = 0; mt < 4; ++mt)
                acc[mt] = MFMA16(lo, pb[2*q][mt], acc[mt]);
            #pragma unroll
            for (int mt = 0; mt < 4; ++mt)
                acc[mt] = MFMA16(hi, pb[2*q + 1][mt], acc[mt]);
        }
        const float4 w2v = *(const float4*)(W2 + t1*16 + g*4);  // W2[16t1+4g+r]
        #pragma unroll
        for (int mt = 0; mt < 4; ++mt) {
            zp[mt] = fmaf(clamp01(acc[mt][0]), w2v.x, zp[mt]);
            zp[mt] = fmaf(clamp01(acc[mt][1]), w2v.y, zp[mt]);
            zp[mt] = fmaf(clamp01(acc[mt][2]), w2v.z, zp[mt]);
            zp[mt] = fmaf(clamp01(acc[mt][3]), w2v.w, zp[mt]);
        }
    }

    // ---- reduce over g-groups (4 lanes per pt-column), sigmoid, store ------
    float zr[4];
    #pragma unroll
    for (int mt = 0; mt < 4; ++mt) {
        float v = zp[mt];
        v += __shfl_xor(v, 16);
        v += __shfl_xor(v, 32);
        zr[mt] = v;                               // full z for pt=16mt+c
    }
    float z = (g == 0) ? zr[0] : (g == 1) ? zr[1] : (g == 2) ? zr[2] : zr[3];
    z += b2[0];
    z = 1.0f / (1.0f + __expf(-z));
    if (p < N) out[p] = z;                        // pt = 16g+c = lane: coalesced
}

extern "C" void kernel_launch(void* const* d_in, const int* in_sizes, int n_in,
                              void* d_out, int out_size, void* d_ws, size_t ws_size,
                              hipStream_t stream) {
    const float* x     = (const float*)d_in[0];
    const float* emb   = (const float*)d_in[1];
    const float* em0_w = (const float*)d_in[2];
    const float* em1_w = (const float*)d_in[3];
    const float* W0    = (const float*)d_in[4];
    const float* b0    = (const float*)d_in[5];
    const float* W1    = (const float*)d_in[6];
    const float* b1    = (const float*)d_in[7];
    const float* W2    = (const float*)d_in[8];
    const float* b2    = (const float*)d_in[9];
    float* out = (float*)d_out;
    const int N = in_sizes[1];

    unsigned short* ws = (unsigned short*)d_ws;   // 514144 B used

    pack_all<<<(WS_TOT + 255) / 256, 256, 0, stream>>>(W0, W1, em0_w, em1_w, ws);
    const int nb = (N + 63) / 64;
    fused_mlp<<<nb, 64, 0, stream>>>(x, emb, W0, b0, b1, W2, b2, ws, out, N);
}

// Round 15
// 77.120 us; speedup vs baseline: 2.8269x; 1.0019x over previous
//
#include <hip/hip_runtime.h>
#include <hip/hip_bf16.h>

typedef _Float16 f16x8 __attribute__((ext_vector_type(8)));
typedef _Float16 f16x4 __attribute__((ext_vector_type(4)));
typedef _Float16 f16x2 __attribute__((ext_vector_type(2)));
typedef __fp16   fp16v2 __attribute__((ext_vector_type(2)));   // cvt_pkrtz return type
typedef float    f32x4 __attribute__((ext_vector_type(4)));

#define E_TOT   6572
#define E4_TOT  1643
#define RSDW    36      // LDS row stride dwords (144 B = 128 B feat + pad); 36%32=4
#define SETB    (64 * RSDW * 4)                   // 9216 B per point-set

// d_ws layout (ushort indices):
// [0,8192) W0p (16 frags) | [8192,20480) W1p16 paired |
// [20480,178208) em0h [6572][24] | [178208,257072) em1h [1643][48]   (all fp16)
#define W1P_OFF  8192
#define EM0B_OFF 20480
#define EM1B_OFF 178208
#define WS_TOT   257072

#if __has_builtin(__builtin_amdgcn_mfma_f32_16x16x16f16)
static __device__ __forceinline__ f32x4 MFMA16(f16x4 a, f16x4 b, f32x4 c) {
    return __builtin_amdgcn_mfma_f32_16x16x16f16(a, b, c, 0, 0, 0);
}
#else
static __device__ __forceinline__ f32x4 MFMA16(f16x4 a, f16x4 b, f32x4 c) {
    asm volatile("v_mfma_f32_16x16x16_f16 %0, %1, %2, %0"
                 : "+v"(c) : "v"(a), "v"(b));
    return c;
}
#endif

static __device__ __forceinline__ float clamp01(float v) {
    return __builtin_amdgcn_fmed3f(v, 0.0f, 1.0f);
}
static __device__ __forceinline__ unsigned cvt_pk_c01(float lo, float hi) {
    union { fp16v2 h; unsigned u; } r;
    r.h = __builtin_amdgcn_cvt_pkrtz(clamp01(lo), clamp01(hi));
    return r.u;
}
// packed-f16 lerp of one dword (2 elems): 2 VALU ops (v_pk_add + v_pk_fma)
static __device__ __forceinline__ unsigned lerp_h2(unsigned a, unsigned b, f16x2 p2) {
    union { unsigned u; f16x2 h; } A, B, R;
    A.u = a; B.u = b;
    R.h = A.h + p2 * (B.h - A.h);
    return R.u;
}
static __device__ __forceinline__ int bperm_i(int pt, int v) {
    return __builtin_amdgcn_ds_bpermute(pt << 2, v);
}
static __device__ __forceinline__ float bperm_f(int pt, float v) {
    union { float f; int i; } u, r;
    u.f = v;
    r.i = __builtin_amdgcn_ds_bpermute(pt << 2, u.i);
    return r.f;
}

// Feature k-order (PERMUTED for aligned cooperative writes):
//   k 0..43  = em1 col k      (W0 row 22+k)
//   k 44..63 = em0 col (k-44) (W0 row k-42)
// W0p: 16x16x32 f16 A-frag order, K=64:
//   frag(t,s<2), lane l, elem e <- W0[wrow(k)][n=16t+(l&15)], k = 32s+8*(l>>4)+e
// W1p16 (PAIRED x16 A-frags): pair p2 = q*6+t1, lane l, half h, e2<4
//   <- W1[k = 16*(2q+h)+4*(l>>4)+e2][n = 16t1+(l&15)]
// em0h: f16 [6572][24] (20 cols + 4 zero-pad); em1h: f16 [1643][48] (44 + 4 pad).
__global__ void pack_all(const float* __restrict__ W0, const float* __restrict__ W1,
                         const float* __restrict__ em0_w, const float* __restrict__ em1_w,
                         unsigned short* __restrict__ ws)
{
    int id = blockIdx.x * 256 + threadIdx.x;
    if (id >= WS_TOT) return;
    union { _Float16 h; unsigned short u; } cv;
    if (id < W1P_OFF) {                            // W0p: f = t*2+s, t<8, s<2
        int e = id & 7, l = (id >> 3) & 63, f = id >> 9;
        int g = l >> 4, c = l & 15;
        int s = f & 1, t = f >> 1;
        int k = s * 32 + g * 8 + e, n = t * 16 + c;
        int wrow = (k < 44) ? (22 + k) : (k - 42);  // em1-first permuted order
        cv.h = (_Float16)W0[wrow * 128 + n];
        ws[id] = cv.u;
    } else if (id < EM0B_OFF) {                    // W1p16 paired
        int id1 = id - W1P_OFF;
        int e2 = id1 & 3, h = (id1 >> 2) & 1, l = (id1 >> 3) & 63, p2 = id1 >> 9;
        int g = l >> 4, c = l & 15;
        int q = p2 / 6, t1 = p2 - 6 * q;
        int s1 = 2 * q + h;
        int k = 16 * s1 + 4 * g + e2, n = 16 * t1 + c;
        cv.h = (_Float16)W1[k * 96 + n];
        ws[id] = cv.u;
    } else if (id < EM1B_OFF) {                    // em0h [6572][24]
        int qd = id - EM0B_OFF;
        int row = qd / 24, col = qd - row * 24;
        cv.h = (_Float16)(col < 20 ? em0_w[row * 20 + col] : 0.0f);
        ws[id] = cv.u;
    } else {                                       // em1h [1643][48]
        int qd = id - EM1B_OFF;
        int row = qd / 48, col = qd - row * 48;
        cv.h = (_Float16)(col < 44 ? em1_w[row * 44 + col] : 0.0f);
        ws[id] = cv.u;
    }
}

// Swapped-operand f16 MFMA MLP; TWO 64-pt sets per wave. Phase A (cooperative
// gather+lerp) runs for BOTH sets up front so all global-load latency overlaps
// once; then each set is computed fully from its LDS feature block. Set-1's
// in-flight state during set-0 compute is LDS-only -> register peak unchanged.
__global__ __launch_bounds__(64, 3) void fused_mlp(
    const float* __restrict__ x, const float* __restrict__ emb,
    const float* __restrict__ W0, const float* __restrict__ b0,
    const float* __restrict__ b1,
    const float* __restrict__ W2, const float* __restrict__ b2,
    const unsigned short* __restrict__ ws,
    float* __restrict__ out, int N)
{
    __shared__ __align__(16) char smem[2 * SETB];   // 18432 B
    const unsigned short* W0p   = ws;
    const unsigned short* W1p16 = ws + W1P_OFF;
    const unsigned short* em0h  = ws + EM0B_OFF;
    const unsigned short* em1h  = ws + EM1B_OFF;

    const int lane  = threadIdx.x;                // one wave per block
    const int g     = lane >> 4, c = lane & 15;
    const int pbase = blockIdx.x * 128;

    // ---- Phase A for both sets: cooperative gather+lerp -> feature rows ----
    float2 xvs[2];
    #pragma unroll
    for (int set = 0; set < 2; ++set) {
        const int pcx = min(pbase + set * 64 + lane, N - 1);
        const float t  = emb[pcx];
        const int   i0 = (int)t;
        const float pf = t - (float)i0;
        const float t4 = t * 0.25f;
        const int   j0 = (int)t4;
        int   jb = j0;  float qf = t4 - (float)j0;
        if (j0 >= E4_TOT - 1) { jb = E4_TOT - 2; qf = 1.0f; }
        xvs[set] = *(const float2*)(x + 2 * pcx);
        char* base_lds = smem + set * SETB;

        // em1 (44 cols): 6 x 16B chunks/pt; slot G=it*64+lane -> pt=G/6, j=G%6
        #pragma unroll
        for (int it = 0; it < 6; ++it) {
            const int Gx = it * 64 + lane;
            const int pt = Gx / 6, j = Gx - pt * 6;
            const int   jbp = bperm_i(pt, jb);
            const float qfp = bperm_f(pt, qf);
            const unsigned short* src = em1h + jbp * 48 + j * 8;
            const uint4 r0 = *(const uint4*)(src);
            const uint4 r1 = *(const uint4*)(src + 48);
            const f16x2 q2 = {(_Float16)qfp, (_Float16)qfp};
            *(uint4*)(base_lds + pt * (RSDW * 4) + j * 16) =
                make_uint4(lerp_h2(r0.x, r1.x, q2), lerp_h2(r0.y, r1.y, q2),
                           lerp_h2(r0.z, r1.z, q2), lerp_h2(r0.w, r1.w, q2));
        }
        // em0 (20 cols): 5 x 8B chunks/pt; overwrites em1's j=5 pad (bytes 88+)
        #pragma unroll
        for (int it = 0; it < 5; ++it) {
            const int Gx = it * 64 + lane;
            const int pt = Gx / 5, j = Gx - pt * 5;
            const int   i0p = bperm_i(pt, i0);
            const float pfp = bperm_f(pt, pf);
            const unsigned short* src = em0h + i0p * 24 + j * 4;
            const uint2 r0 = *(const uint2*)(src);
            const uint2 r1 = *(const uint2*)(src + 24);
            const f16x2 p2 = {(_Float16)pfp, (_Float16)pfp};
            *(uint2*)(base_lds + pt * (RSDW * 4) + 88 + j * 8) =
                make_uint2(lerp_h2(r0.x, r1.x, p2), lerp_h2(r0.y, r1.y, p2));
        }
    }
    // no barrier: single wave; LDS ops ordered by lgkmcnt in program order

    // ---- compute each set fully from its LDS feature block -----------------
    #pragma unroll
    for (int set = 0; set < 2; ++set) {
        const char* base_lds = smem + set * SETB;
        const float2 xv = xvs[set];

        float xq0[4], xq1[4];
        #pragma unroll
        for (int mt = 0; mt < 4; ++mt) {
            xq0[mt] = bperm_f(16*mt + c, xv.x);
            xq1[mt] = bperm_f(16*mt + c, xv.y);
        }

        f16x8 a0f[4][2];
        #pragma unroll
        for (int mt = 0; mt < 4; ++mt)
            #pragma unroll
            for (int s = 0; s < 2; ++s)
                a0f[mt][s] = *(const f16x8*)(base_lds + ((16*mt + c) * RSDW) * 4 + 64*s + 16*g);

        // Layer 0 (16x16x32 f16, K=64, swapped): D0[out=16t+4g+r][pt=16mt+c]
        union U2S { uint2 u; f16x4 s; };
        f16x4 pb[8][4];
        #pragma unroll
        for (int tt = 0; tt < 8; ++tt) {
            f16x8 bw[2];
            #pragma unroll
            for (int s = 0; s < 2; ++s)
                bw[s] = *(const f16x8*)(W0p + ((tt*2 + s) << 9) + (lane << 3));
            const float4 b0v = *(const float4*)(b0 + tt*16 + g*4);
            f32x4 acc[4];
            #pragma unroll
            for (int mt = 0; mt < 4; ++mt) acc[mt] = f32x4{b0v.x, b0v.y, b0v.z, b0v.w};
            #pragma unroll
            for (int s = 0; s < 2; ++s)
                #pragma unroll
                for (int mt = 0; mt < 4; ++mt)
                    acc[mt] = __builtin_amdgcn_mfma_f32_16x16x32_f16(bw[s], a0f[mt][s], acc[mt], 0, 0, 0);
            const float4 wa = *(const float4*)(W0 + tt*16 + g*4);        // W0[0][n]
            const float4 wb = *(const float4*)(W0 + 128 + tt*16 + g*4);  // W0[1][n]
            const float wa_[4] = {wa.x, wa.y, wa.z, wa.w};
            const float wb_[4] = {wb.x, wb.y, wb.z, wb.w};
            #pragma unroll
            for (int mt = 0; mt < 4; ++mt) {
                float v0 = fmaf(xq0[mt], wa_[0], fmaf(xq1[mt], wb_[0], acc[mt][0]));
                float v1 = fmaf(xq0[mt], wa_[1], fmaf(xq1[mt], wb_[1], acc[mt][1]));
                float v2 = fmaf(xq0[mt], wa_[2], fmaf(xq1[mt], wb_[2], acc[mt][2]));
                float v3 = fmaf(xq0[mt], wa_[3], fmaf(xq1[mt], wb_[3], acc[mt][3]));
                U2S u2;
                u2.u = make_uint2(cvt_pk_c01(v0, v1), cvt_pk_c01(v2, v3));
                pb[tt][mt] = u2.s;                // h1[k=16t+4g+e][pt=16mt+c]
            }
        }

        // Layer 1 (16x16x16 f16, swapped) + fused W2, no LDS
        float zp[4] = {0.f, 0.f, 0.f, 0.f};
        #pragma unroll
        for (int t1 = 0; t1 < 6; ++t1) {
            const float4 b1v = *(const float4*)(b1 + t1*16 + g*4);
            f32x4 acc[4];
            #pragma unroll
            for (int mt = 0; mt < 4; ++mt) acc[mt] = f32x4{b1v.x, b1v.y, b1v.z, b1v.w};
            #pragma unroll
            for (int q = 0; q < 4; ++q) {         // one b128 = frags s1=2q,2q+1
                const f16x8 pr = *(const f16x8*)(W1p16 + ((q*6 + t1) << 9) + (lane << 3));
                f16x4 lo, hi;
                lo[0]=pr[0]; lo[1]=pr[1]; lo[2]=pr[2]; lo[3]=pr[3];
                hi[0]=pr[4]; hi[1]=pr[5]; hi[2]=pr[6]; hi[3]=pr[7];
                #pragma unroll
                for (int mt = 0; mt < 4; ++mt)
                    acc[mt] = MFMA16(lo, pb[2*q][mt], acc[mt]);
                #pragma unroll
                for (int mt = 0; mt < 4; ++mt)
                    acc[mt] = MFMA16(hi, pb[2*q + 1][mt], acc[mt]);
            }
            const float4 w2v = *(const float4*)(W2 + t1*16 + g*4);
            #pragma unroll
            for (int mt = 0; mt < 4; ++mt) {
                zp[mt] = fmaf(clamp01(acc[mt][0]), w2v.x, zp[mt]);
                zp[mt] = fmaf(clamp01(acc[mt][1]), w2v.y, zp[mt]);
                zp[mt] = fmaf(clamp01(acc[mt][2]), w2v.z, zp[mt]);
                zp[mt] = fmaf(clamp01(acc[mt][3]), w2v.w, zp[mt]);
            }
        }

        // reduce over g-groups (4 lanes per pt-column), sigmoid, store
        float zr[4];
        #pragma unroll
        for (int mt = 0; mt < 4; ++mt) {
            float v = zp[mt];
            v += __shfl_xor(v, 16);
            v += __shfl_xor(v, 32);
            zr[mt] = v;
        }
        float z = (g == 0) ? zr[0] : (g == 1) ? zr[1] : (g == 2) ? zr[2] : zr[3];
        z += b2[0];
        z = 1.0f / (1.0f + __expf(-z));
        const int px = pbase + set * 64 + lane;   // pt = 16g+c = lane: coalesced
        if (px < N) out[px] = z;
    }
}

extern "C" void kernel_launch(void* const* d_in, const int* in_sizes, int n_in,
                              void* d_out, int out_size, void* d_ws, size_t ws_size,
                              hipStream_t stream) {
    const float* x     = (const float*)d_in[0];
    const float* emb   = (const float*)d_in[1];
    const float* em0_w = (const float*)d_in[2];
    const float* em1_w = (const float*)d_in[3];
    const float* W0    = (const float*)d_in[4];
    const float* b0    = (const float*)d_in[5];
    const float* W1    = (const float*)d_in[6];
    const float* b1    = (const float*)d_in[7];
    const float* W2    = (const float*)d_in[8];
    const float* b2    = (const float*)d_in[9];
    float* out = (float*)d_out;
    const int N = in_sizes[1];

    unsigned short* ws = (unsigned short*)d_ws;   // 514144 B used

    pack_all<<<(WS_TOT + 255) / 256, 256, 0, stream>>>(W0, W1, em0_w, em1_w, ws);
    const int nb = (N + 127) / 128;
    fused_mlp<<<nb, 64, 0, stream>>>(x, emb, W0, b0, b1, W2, b2, ws, out, N);
}

// Round 16
// 70.558 us; speedup vs baseline: 3.0898x; 1.0930x over previous
//
#include <hip/hip_runtime.h>
#include <hip/hip_bf16.h>

typedef _Float16 f16x8 __attribute__((ext_vector_type(8)));
typedef _Float16 f16x4 __attribute__((ext_vector_type(4)));
typedef _Float16 f16x2 __attribute__((ext_vector_type(2)));
typedef __fp16   fp16v2 __attribute__((ext_vector_type(2)));   // cvt_pkrtz return type
typedef float    f32x4 __attribute__((ext_vector_type(4)));

#define E_TOT   6572
#define E4_TOT  1643
#define RSDW    36      // LDS feature row stride dwords (144 B); 36%32=4
#define SETB    (64 * RSDW * 4)                   // 9216 B per wave's feature slice

// d_ws layout (ushort indices):
// [0,8192) W0p (16 frags) | [8192,20480) W1p16 paired |
// [20480,178208) em0h [6572][24] | [178208,257072) em1h [1643][48]   (all fp16)
#define W1P_OFF  8192
#define EM0B_OFF 20480
#define EM1B_OFF 178208
#define WS_TOT   257072

#if __has_builtin(__builtin_amdgcn_mfma_f32_16x16x16f16)
static __device__ __forceinline__ f32x4 MFMA16(f16x4 a, f16x4 b, f32x4 c) {
    return __builtin_amdgcn_mfma_f32_16x16x16f16(a, b, c, 0, 0, 0);
}
#else
static __device__ __forceinline__ f32x4 MFMA16(f16x4 a, f16x4 b, f32x4 c) {
    asm volatile("v_mfma_f32_16x16x16_f16 %0, %1, %2, %0"
                 : "+v"(c) : "v"(a), "v"(b));
    return c;
}
#endif

static __device__ __forceinline__ float clamp01(float v) {
    return __builtin_amdgcn_fmed3f(v, 0.0f, 1.0f);
}
static __device__ __forceinline__ unsigned cvt_pk_c01(float lo, float hi) {
    union { fp16v2 h; unsigned u; } r;
    r.h = __builtin_amdgcn_cvt_pkrtz(clamp01(lo), clamp01(hi));
    return r.u;
}
// packed-f16 lerp of one dword (2 elems): 2 VALU ops (v_pk_add + v_pk_fma)
static __device__ __forceinline__ unsigned lerp_h2(unsigned a, unsigned b, f16x2 p2) {
    union { unsigned u; f16x2 h; } A, B, R;
    A.u = a; B.u = b;
    R.h = A.h + p2 * (B.h - A.h);
    return R.u;
}
static __device__ __forceinline__ int bperm_i(int pt, int v) {
    return __builtin_amdgcn_ds_bpermute(pt << 2, v);
}
static __device__ __forceinline__ float bperm_f(int pt, float v) {
    union { float f; int i; } u, r;
    u.f = v;
    r.i = __builtin_amdgcn_ds_bpermute(pt << 2, u.i);
    return r.f;
}

// Feature k-order (PERMUTED for aligned cooperative writes):
//   k 0..43  = em1 col k      (W0 row 22+k)
//   k 44..63 = em0 col (k-44) (W0 row k-42)
// W0p: 16x16x32 f16 A-frag order, K=64:
//   frag(t,s<2), lane l, elem e <- W0[wrow(k)][n=16t+(l&15)], k = 32s+8*(l>>4)+e
// W1p16 (PAIRED x16 A-frags): pair p2 = q*6+t1, lane l, half h, e2<4
//   <- W1[k = 16*(2q+h)+4*(l>>4)+e2][n = 16t1+(l&15)]
// em0h: f16 [6572][24] (20 cols + 4 zero-pad); em1h: f16 [1643][48] (44 + 4 pad).
__global__ void pack_all(const float* __restrict__ W0, const float* __restrict__ W1,
                         const float* __restrict__ em0_w, const float* __restrict__ em1_w,
                         unsigned short* __restrict__ ws)
{
    int id = blockIdx.x * 256 + threadIdx.x;
    if (id >= WS_TOT) return;
    union { _Float16 h; unsigned short u; } cv;
    if (id < W1P_OFF) {                            // W0p: f = t*2+s, t<8, s<2
        int e = id & 7, l = (id >> 3) & 63, f = id >> 9;
        int g = l >> 4, c = l & 15;
        int s = f & 1, t = f >> 1;
        int k = s * 32 + g * 8 + e, n = t * 16 + c;
        int wrow = (k < 44) ? (22 + k) : (k - 42);  // em1-first permuted order
        cv.h = (_Float16)W0[wrow * 128 + n];
        ws[id] = cv.u;
    } else if (id < EM0B_OFF) {                    // W1p16 paired
        int id1 = id - W1P_OFF;
        int e2 = id1 & 3, h = (id1 >> 2) & 1, l = (id1 >> 3) & 63, p2 = id1 >> 9;
        int g = l >> 4, c = l & 15;
        int q = p2 / 6, t1 = p2 - 6 * q;
        int s1 = 2 * q + h;
        int k = 16 * s1 + 4 * g + e2, n = 16 * t1 + c;
        cv.h = (_Float16)W1[k * 96 + n];
        ws[id] = cv.u;
    } else if (id < EM1B_OFF) {                    // em0h [6572][24]
        int qd = id - EM0B_OFF;
        int row = qd / 24, col = qd - row * 24;
        cv.h = (_Float16)(col < 20 ? em0_w[row * 20 + col] : 0.0f);
        ws[id] = cv.u;
    } else {                                       // em1h [1643][48]
        int qd = id - EM1B_OFF;
        int row = qd / 48, col = qd - row * 48;
        cv.h = (_Float16)(col < 44 ? em1_w[row * 44 + col] : 0.0f);
        ws[id] = cv.u;
    }
}

// Swapped-operand f16 MFMA MLP; 4 waves/block (256 pts). W1p (24 KB, the
// larger per-batch W stream) is staged ONCE per block into LDS and read as
// bank-perfect ds_read_b128 -> per-point W1 L2 traffic drops 6.7x, and W0p
// (16 KB) + hot table rows now fit L1. Features remain per-wave LDS slices.
__global__ __launch_bounds__(256, 2) void fused_mlp(
    const float* __restrict__ x, const float* __restrict__ emb,
    const float* __restrict__ W0, const float* __restrict__ b0,
    const float* __restrict__ b1,
    const float* __restrict__ W2, const float* __restrict__ b2,
    const unsigned short* __restrict__ ws,
    float* __restrict__ out, int N)
{
    __shared__ __align__(16) char smem[4 * SETB + 24576];  // 61440 B
    unsigned short* w1s = (unsigned short*)(smem + 4 * SETB);
    const unsigned short* W0p  = ws;
    const unsigned short* em0h = ws + EM0B_OFF;
    const unsigned short* em1h = ws + EM1B_OFF;

    const int lane = threadIdx.x & 63;
    const int wid  = threadIdx.x >> 6;            // wave 0..3
    const int g    = lane >> 4, c = lane & 15;
    const int p    = blockIdx.x * 256 + wid * 64 + lane;
    const int pc   = min(p, N - 1);
    char* feat_lds = smem + wid * SETB;           // this wave's feature slice

    // ---- stage W1p -> LDS (once per block; 3072 uint4 over 256 threads) ----
    {
        const uint4* src = (const uint4*)(ws + W1P_OFF);
        uint4* dst = (uint4*)w1s;
        #pragma unroll
        for (int i = 0; i < 12; ++i)
            dst[threadIdx.x + i * 256] = src[threadIdx.x + i * 256];
    }

    // ---- own-point params ---------------------------------------------------
    const float t  = emb[pc];
    const int   i0 = (int)t;                      // i0 <= 6570 -> i0+1 valid
    const float pf = t - (float)i0;
    const float t4 = t * 0.25f;                   // exact
    const int   j0 = (int)t4;
    int   jb = j0;  float qf = t4 - (float)j0;
    if (j0 >= E4_TOT - 1) { jb = E4_TOT - 2; qf = 1.0f; }
    const float2 xv = *(const float2*)(x + 2 * pc);

    // ---- Phase A: COOPERATIVE gather+lerp -> this wave's feature rows -------
    // em1 (44 cols): 6 x 16B chunks/pt; slot G = it*64+lane -> pt=G/6, j=G%6
    #pragma unroll
    for (int it = 0; it < 6; ++it) {
        const int Gx = it * 64 + lane;
        const int pt = Gx / 6, j = Gx - pt * 6;
        const int   jbp = bperm_i(pt, jb);
        const float qfp = bperm_f(pt, qf);
        const unsigned short* src = em1h + jbp * 48 + j * 8;
        const uint4 r0 = *(const uint4*)(src);
        const uint4 r1 = *(const uint4*)(src + 48);
        const f16x2 q2 = {(_Float16)qfp, (_Float16)qfp};
        *(uint4*)(feat_lds + pt * (RSDW * 4) + j * 16) =
            make_uint4(lerp_h2(r0.x, r1.x, q2), lerp_h2(r0.y, r1.y, q2),
                       lerp_h2(r0.z, r1.z, q2), lerp_h2(r0.w, r1.w, q2));
    }
    // em0 (20 cols): 5 x 8B chunks/pt; overwrites em1's j=5 pad (bytes 88+)
    #pragma unroll
    for (int it = 0; it < 5; ++it) {
        const int Gx = it * 64 + lane;
        const int pt = Gx / 5, j = Gx - pt * 5;
        const int   i0p = bperm_i(pt, i0);
        const float pfp = bperm_f(pt, pf);
        const unsigned short* src = em0h + i0p * 24 + j * 4;
        const uint2 r0 = *(const uint2*)(src);
        const uint2 r1 = *(const uint2*)(src + 24);
        const f16x2 p2 = {(_Float16)pfp, (_Float16)pfp};
        *(uint2*)(feat_lds + pt * (RSDW * 4) + 88 + j * 8) =
            make_uint2(lerp_h2(r0.x, r1.x, p2), lerp_h2(r0.y, r1.y, p2));
    }

    __syncthreads();   // w1s visible to all waves (features are wave-local)

    // ---- x of this lane's column-points via lane exchange ------------------
    float xq0[4], xq1[4];
    #pragma unroll
    for (int mt = 0; mt < 4; ++mt) {
        xq0[mt] = bperm_f(16*mt + c, xv.x);
        xq1[mt] = bperm_f(16*mt + c, xv.y);
    }

    // ---- feature B-frags: lane (g,c) <- feat[k=32s+8g+e][pt=16mt+c] --------
    f16x8 a0f[4][2];
    #pragma unroll
    for (int mt = 0; mt < 4; ++mt)
        #pragma unroll
        for (int s = 0; s < 2; ++s)
            a0f[mt][s] = *(const f16x8*)(feat_lds + ((16*mt + c) * RSDW) * 4 + 64*s + 16*g);

    // ---- Layer 0 (16x16x32 f16, K=64, swapped): D0[out=16t+4g+r][pt=16mt+c] -
    union U2S { uint2 u; f16x4 s; };
    f16x4 pb[8][4];
    #pragma unroll
    for (int tt = 0; tt < 8; ++tt) {
        f16x8 bw[2];
        #pragma unroll
        for (int s = 0; s < 2; ++s)
            bw[s] = *(const f16x8*)(W0p + ((tt*2 + s) << 9) + (lane << 3));
        const float4 b0v = *(const float4*)(b0 + tt*16 + g*4);  // b0[16t+4g+r]
        f32x4 acc[4];
        #pragma unroll
        for (int mt = 0; mt < 4; ++mt) acc[mt] = f32x4{b0v.x, b0v.y, b0v.z, b0v.w};
        #pragma unroll
        for (int s = 0; s < 2; ++s)
            #pragma unroll
            for (int mt = 0; mt < 4; ++mt)
                acc[mt] = __builtin_amdgcn_mfma_f32_16x16x32_f16(bw[s], a0f[mt][s], acc[mt], 0, 0, 0);
        const float4 wa = *(const float4*)(W0 + tt*16 + g*4);        // W0[0][n]
        const float4 wb = *(const float4*)(W0 + 128 + tt*16 + g*4);  // W0[1][n]
        const float wa_[4] = {wa.x, wa.y, wa.z, wa.w};
        const float wb_[4] = {wb.x, wb.y, wb.z, wb.w};
        #pragma unroll
        for (int mt = 0; mt < 4; ++mt) {
            float v0 = fmaf(xq0[mt], wa_[0], fmaf(xq1[mt], wb_[0], acc[mt][0]));
            float v1 = fmaf(xq0[mt], wa_[1], fmaf(xq1[mt], wb_[1], acc[mt][1]));
            float v2 = fmaf(xq0[mt], wa_[2], fmaf(xq1[mt], wb_[2], acc[mt][2]));
            float v3 = fmaf(xq0[mt], wa_[3], fmaf(xq1[mt], wb_[3], acc[mt][3]));
            U2S u2;
            u2.u = make_uint2(cvt_pk_c01(v0, v1), cvt_pk_c01(v2, v3));
            pb[tt][mt] = u2.s;                    // h1[k=16t+4g+e][pt=16mt+c]
        }
    }

    // ---- Layer 1 (16x16x16 f16, swapped) + fused W2; W1 frags from LDS -----
    float zp[4] = {0.f, 0.f, 0.f, 0.f};
    #pragma unroll
    for (int t1 = 0; t1 < 6; ++t1) {
        const float4 b1v = *(const float4*)(b1 + t1*16 + g*4);  // b1[16t1+4g+r]
        f32x4 acc[4];
        #pragma unroll
        for (int mt = 0; mt < 4; ++mt) acc[mt] = f32x4{b1v.x, b1v.y, b1v.z, b1v.w};
        #pragma unroll
        for (int q = 0; q < 4; ++q) {             // one LDS b128 = frags s1=2q,2q+1
            const f16x8 pr = *(const f16x8*)(w1s + ((q*6 + t1) << 9) + (lane << 3));
            f16x4 lo, hi;
            lo[0]=pr[0]; lo[1]=pr[1]; lo[2]=pr[2]; lo[3]=pr[3];
            hi[0]=pr[4]; hi[1]=pr[5]; hi[2]=pr[6]; hi[3]=pr[7];
            #pragma unroll
            for (int mt = 0; mt < 4; ++mt)
                acc[mt] = MFMA16(lo, pb[2*q][mt], acc[mt]);
            #pragma unroll
            for (int mt = 0; mt < 4; ++mt)
                acc[mt] = MFMA16(hi, pb[2*q + 1][mt], acc[mt]);
        }
        const float4 w2v = *(const float4*)(W2 + t1*16 + g*4);  // W2[16t1+4g+r]
        #pragma unroll
        for (int mt = 0; mt < 4; ++mt) {
            zp[mt] = fmaf(clamp01(acc[mt][0]), w2v.x, zp[mt]);
            zp[mt] = fmaf(clamp01(acc[mt][1]), w2v.y, zp[mt]);
            zp[mt] = fmaf(clamp01(acc[mt][2]), w2v.z, zp[mt]);
            zp[mt] = fmaf(clamp01(acc[mt][3]), w2v.w, zp[mt]);
        }
    }

    // ---- reduce over g-groups (4 lanes per pt-column), sigmoid, store ------
    float zr[4];
    #pragma unroll
    for (int mt = 0; mt < 4; ++mt) {
        float v = zp[mt];
        v += __shfl_xor(v, 16);
        v += __shfl_xor(v, 32);
        zr[mt] = v;                               // full z for pt=16mt+c
    }
    float z = (g == 0) ? zr[0] : (g == 1) ? zr[1] : (g == 2) ? zr[2] : zr[3];
    z += b2[0];
    z = 1.0f / (1.0f + __expf(-z));
    if (p < N) out[p] = z;                        // pt = 16g+c = lane: coalesced
}

extern "C" void kernel_launch(void* const* d_in, const int* in_sizes, int n_in,
                              void* d_out, int out_size, void* d_ws, size_t ws_size,
                              hipStream_t stream) {
    const float* x     = (const float*)d_in[0];
    const float* emb   = (const float*)d_in[1];
    const float* em0_w = (const float*)d_in[2];
    const float* em1_w = (const float*)d_in[3];
    const float* W0    = (const float*)d_in[4];
    const float* b0    = (const float*)d_in[5];
    const float* W1    = (const float*)d_in[6];
    const float* b1    = (const float*)d_in[7];
    const float* W2    = (const float*)d_in[8];
    const float* b2    = (const float*)d_in[9];
    float* out = (float*)d_out;
    const int N = in_sizes[1];

    unsigned short* ws = (unsigned short*)d_ws;   // 514144 B used

    pack_all<<<(WS_TOT + 255) / 256, 256, 0, stream>>>(W0, W1, em0_w, em1_w, ws);
    const int nb = (N + 255) / 256;
    fused_mlp<<<nb, 256, 0, stream>>>(x, emb, W0, b0, b1, W2, b2, ws, out, N);
}